// Round 1
// baseline (944.756 us; speedup 1.0000x reference)
//
#include <hip/hip_runtime.h>
#include <math.h>

#define B_    2
#define S_    2048
#define H_    2048
#define NH_   16
#define NOPE_ 128
#define ROPE_ 64
#define VDIM_ 128
#define RANK_ 512
#define QHD_  192   // NOPE + ROPE
#define DTOT_ 576   // RANK + ROPE

typedef short short8 __attribute__((ext_vector_type(8)));
typedef float f32x4 __attribute__((ext_vector_type(4)));

__device__ __forceinline__ unsigned short f2bf(float f) {
    unsigned u = __float_as_uint(f);
    u += 0x7fffu + ((u >> 16) & 1u);
    return (unsigned short)(u >> 16);
}
__device__ __forceinline__ float bf2f(unsigned short u) {
    return __uint_as_float((unsigned)u << 16);
}
__device__ __forceinline__ unsigned pack2bf(float a, float b) {
    return (unsigned)f2bf(a) | ((unsigned)f2bf(b) << 16);
}
__device__ __forceinline__ unsigned long long pack4bf(float a, float b, float c, float d) {
    return (unsigned long long)pack2bf(a, b) | ((unsigned long long)pack2bf(c, d) << 32);
}
union i4s8 { int4 i; short8 s; };

// Async global->LDS, 16B per lane. LDS dest = wave-uniform base + lane*16.
typedef __attribute__((address_space(3))) unsigned int lds_u32_t;
typedef __attribute__((address_space(1))) const unsigned int glob_u32_t;
__device__ __forceinline__ void async_copy16(const unsigned short* g, unsigned short* l) {
    __builtin_amdgcn_global_load_lds((glob_u32_t*)g, (lds_u32_t*)l, 16, 0, 0);
}

// ---------------------------------------------------------------------------
// cast fp32 -> bf16, 4 elems/thread.
// ---------------------------------------------------------------------------
__global__ __launch_bounds__(256) void cast_bf16(const float* __restrict__ in,
                                                 unsigned short* __restrict__ out)
{
    const size_t i = ((size_t)blockIdx.x * 256 + threadIdx.x) * 4;
    float4 v = *(const float4*)(in + i);
    *(unsigned long long*)(out + i) = pack4bf(v.x, v.y, v.z, v.w);
}

// ---------------------------------------------------------------------------
// Transpose + cast: in fp32 [Rr][Cc] (batched) -> out bf16 [Cc][Rr].
// grid (Rr/64, Cc/64, batch), 256 threads.
// ---------------------------------------------------------------------------
__global__ __launch_bounds__(256) void transpose_w(const float* __restrict__ in,
                                                   unsigned short* __restrict__ out,
                                                   int Rr, int Cc,
                                                   size_t inBatch, size_t outBatch)
{
    __shared__ unsigned short tl[64][72];
    in  += (size_t)blockIdx.z * inBatch;
    out += (size_t)blockIdx.z * outBatch;
    const int t  = threadIdx.x;
    const int r0 = blockIdx.x * 64;
    const int c0 = blockIdx.y * 64;
    const int lr = t >> 4;
    const int lc = (t & 15) * 4;
#pragma unroll
    for (int r = 0; r < 4; ++r) {
        float4 v = *(const float4*)(in + (size_t)(r0 + lr*4 + r) * Cc + c0 + lc);
        tl[lr*4 + r][lc+0] = f2bf(v.x); tl[lr*4 + r][lc+1] = f2bf(v.y);
        tl[lr*4 + r][lc+2] = f2bf(v.z); tl[lr*4 + r][lc+3] = f2bf(v.w);
    }
    __syncthreads();
#pragma unroll
    for (int r = 0; r < 4; ++r) {
        ushort4 v;
        v.x = tl[lc+0][lr*4+r]; v.y = tl[lc+1][lr*4+r];
        v.z = tl[lc+2][lr*4+r]; v.w = tl[lc+3][lr*4+r];
        *(ushort4*)(out + (size_t)(c0 + lr*4 + r) * Rr + r0 + lc) = v;
    }
}

// ---------------------------------------------------------------------------
// bf16 MFMA GEMM, m97-style: C = A[M][K](lda) @ Bt^T, Bt bf16 [N][K].
// 128x128 tile, 4 waves, BK=32, global_load_lds staging. N-guard for ragged N.
// ---------------------------------------------------------------------------
#define BGEMM_BODY(STORE_STMT)                                                     \
    __shared__ unsigned short Al[128*32];                                          \
    __shared__ unsigned short Bl[128*32];                                          \
    const int t = threadIdx.x;                                                     \
    const int wv = t >> 6;                                                         \
    const int lane = t & 63;                                                       \
    const int lq = lane & 15, quad = lane >> 4;                                    \
    const int m0 = blockIdx.y * 128, n0 = blockIdx.x * 128;                        \
    const int wrow = (wv >> 1) * 64, wcol = (wv & 1) * 64;                         \
    const int srow = lane >> 2;                                                    \
    const int scol = (lane & 3) * 8;                                               \
    f32x4 acc[4][4] = {};                                                          \
    for (int k0 = 0; k0 < K; k0 += 32) {                                           \
        _Pragma("unroll")                                                          \
        for (int pA = 0; pA < 2; ++pA) {                                           \
            const unsigned short* src =                                            \
                A + (size_t)(m0 + pA*64 + wv*16 + srow) * lda + k0 + scol;         \
            async_copy16(src, &Al[pA*2048 + wv*512]);                              \
        }                                                                          \
        _Pragma("unroll")                                                          \
        for (int pB = 0; pB < 2; ++pB) {                                           \
            int brow = n0 + pB*64 + wv*16 + srow;                                  \
            if (brow > N - 1) brow = N - 1;                                        \
            const unsigned short* src = B + (size_t)brow * K + k0 + scol;          \
            async_copy16(src, &Bl[pB*2048 + wv*512]);                              \
        }                                                                          \
        __syncthreads();                                                           \
        short8 af[4], bf[4];                                                       \
        _Pragma("unroll")                                                          \
        for (int i = 0; i < 4; ++i) {                                              \
            af[i] = *(const short8*)&Al[(wrow + i*16 + lq)*32 + quad*8];           \
            bf[i] = *(const short8*)&Bl[(wcol + i*16 + lq)*32 + quad*8];           \
        }                                                                          \
        _Pragma("unroll")                                                          \
        for (int mi = 0; mi < 4; ++mi)                                             \
            _Pragma("unroll")                                                      \
            for (int ni = 0; ni < 4; ++ni)                                         \
                acc[mi][ni] = __builtin_amdgcn_mfma_f32_16x16x32_bf16(             \
                    af[mi], bf[ni], acc[mi][ni], 0, 0, 0);                         \
        __syncthreads();                                                           \
    }                                                                              \
    _Pragma("unroll")                                                              \
    for (int mi = 0; mi < 4; ++mi)                                                 \
        _Pragma("unroll")                                                          \
        for (int ni = 0; ni < 4; ++ni) {                                           \
            int col = n0 + wcol + ni*16 + lq;                                      \
            if (col < N) {                                                         \
                _Pragma("unroll")                                                  \
                for (int r = 0; r < 4; ++r)                                        \
                    STORE_STMT;                                                    \
            }                                                                      \
        }

__global__ __launch_bounds__(256, 2) void bgemm2(const unsigned short* __restrict__ A,
                                                 int lda,
                                                 const unsigned short* __restrict__ B,
                                                 unsigned short* __restrict__ C,
                                                 int ldc, int K, int N, int qcmode)
{
    if (qcmode) {
        const int z = blockIdx.z;
        A += (size_t)(z >> 4) * S_ * (NH_*QHD_) + (z & 15) * QHD_;
        B += (size_t)(z & 15) * RANK_ * NOPE_;
        C += (size_t)z * S_ * DTOT_;
    }
    BGEMM_BODY(C[(size_t)(m0 + wrow + mi*16 + quad*4 + r) * ldc + col] = f2bf(acc[mi][ni][r]))
}

__global__ __launch_bounds__(256, 2) void bgemm2f(const unsigned short* __restrict__ A,
                                                  int lda,
                                                  const unsigned short* __restrict__ B,
                                                  float* __restrict__ C,
                                                  int ldc, int K, int N)
{
    BGEMM_BODY(C[(size_t)(m0 + wrow + mi*16 + quad*4 + r) * ldc + col] = acc[mi][ni][r])
}

// ---------------------------------------------------------------------------
// Per (b,s) row: RMSNorm ckv (bf16 in) -> k_cat[0:512]; RoPE k_pe -> [512:576].
// ---------------------------------------------------------------------------
__global__ __launch_bounds__(128) void postkv(const unsigned short* __restrict__ ckv_bf,
                                              const float* __restrict__ lnw,
                                              const int*   __restrict__ pos_ids,
                                              const float* __restrict__ cosc,
                                              const float* __restrict__ sinc,
                                              unsigned short* __restrict__ k_cat)
{
    const int row = blockIdx.x;
    const int t   = threadIdx.x;
    const unsigned short* src = ckv_bf + (size_t)row * DTOT_;
    __shared__ float red[128];

    ushort4 v = *(const ushort4*)(src + t * 4);
    float x0 = bf2f(v.x), x1 = bf2f(v.y), x2 = bf2f(v.z), x3 = bf2f(v.w);
    red[t] = x0*x0 + x1*x1 + x2*x2 + x3*x3;
    __syncthreads();
    for (int off = 64; off > 0; off >>= 1) {
        if (t < off) red[t] += red[t + off];
        __syncthreads();
    }
    const float rs = rsqrtf(red[0] / (float)RANK_ + 1e-6f);

    unsigned short* kc = k_cat + (size_t)row * DTOT_;
    *(unsigned long long*)(kc + t*4) =
        pack4bf(x0*rs*lnw[t*4+0], x1*rs*lnw[t*4+1], x2*rs*lnw[t*4+2], x3*rs*lnw[t*4+3]);

    if (t < 32) {
        const int pos = pos_ids[row];
        const float c  = cosc[pos * ROPE_ + t];
        const float sn = sinc[pos * ROPE_ + t];
        const float y0 = bf2f(src[RANK_ + 2*t]);
        const float y1 = bf2f(src[RANK_ + 2*t + 1]);
        kc[RANK_ + t]      = f2bf(y0*c - y1*sn);
        kc[RANK_ + 32 + t] = f2bf(y1*c + y0*sn);
    }
}

// ---------------------------------------------------------------------------
// RoPE q_pe (bf16 in) -> q_cat[...,512:576]. grid = B*S, 512 threads.
// ---------------------------------------------------------------------------
__global__ __launch_bounds__(512) void ropeq(const unsigned short* __restrict__ q_bf,
                                             const int*   __restrict__ pos_ids,
                                             const float* __restrict__ cosc,
                                             const float* __restrict__ sinc,
                                             unsigned short* __restrict__ q_cat)
{
    const int row = blockIdx.x;
    const int t   = threadIdx.x;
    const int h   = t >> 5;
    const int i   = t & 31;
    const int pos = pos_ids[row];
    const float c  = cosc[pos * ROPE_ + i];
    const float sn = sinc[pos * ROPE_ + i];
    const unsigned short* qrow = q_bf + (size_t)row * (NH_*QHD_) + h * QHD_ + NOPE_;
    const float x0 = bf2f(qrow[2*i]);
    const float x1 = bf2f(qrow[2*i + 1]);
    const int b = row >> 11, s = row & 2047;
    unsigned short* qc = q_cat + ((size_t)(b * NH_ + h) * S_ + s) * DTOT_ + RANK_;
    qc[i]      = f2bf(x0*c - x1*sn);
    qc[32 + i] = f2bf(x1*c + x0*sn);
}

// ---------------------------------------------------------------------------
// Vt[b,c,k] = k_cat[b,k,c] for c<512. grid (32, 8, 2).
// ---------------------------------------------------------------------------
__global__ __launch_bounds__(256) void transpose_v(const unsigned short* __restrict__ k_cat,
                                                   unsigned short* __restrict__ vt)
{
    __shared__ unsigned short tl[64][72];
    const int t  = threadIdx.x;
    const int k0 = blockIdx.x * 64;
    const int c0 = blockIdx.y * 64;
    const int b  = blockIdx.z;
    const int lr = t >> 4;
    const int lc = (t & 15) * 4;
#pragma unroll
    for (int r = 0; r < 4; ++r) {
        ushort4 v = *(const ushort4*)(k_cat + ((size_t)b * S_ + k0 + lr*4 + r) * DTOT_ + c0 + lc);
        tl[lr*4 + r][lc+0] = v.x; tl[lr*4 + r][lc+1] = v.y;
        tl[lr*4 + r][lc+2] = v.z; tl[lr*4 + r][lc+3] = v.w;
    }
    __syncthreads();
#pragma unroll
    for (int r = 0; r < 4; ++r) {
        ushort4 v;
        v.x = tl[lc+0][lr*4+r]; v.y = tl[lc+1][lr*4+r];
        v.z = tl[lc+2][lr*4+r]; v.w = tl[lc+3][lr*4+r];
        *(ushort4*)(vt + ((size_t)b * RANK_ + c0 + lr*4 + r) * S_ + k0 + lc) = v;
    }
}

__global__ __launch_bounds__(256) void wcast(const float* __restrict__ w,
                                             unsigned short* __restrict__ wbf)
{
    const size_t i = ((size_t)blockIdx.x * 256 + threadIdx.x) * 4;
    float4 v = *(const float4*)(w + i);
    *(unsigned long long*)(wbf + i) = pack4bf(v.x, v.y, v.z, v.w);
}

// ---------------------------------------------------------------------------
// Flash attention v5: 4 waves/block, 64 q-rows, 2 barriers/tile.
// Changes vs v4 (both target the per-tile critical path; kernel is
// latency-bound at 2 waves/SIMD, MfmaUtil=VALUBusy=22%):
//  (a) T14 async-STAGE split for K: global loads for tile t+1 are issued
//      right after barrier1 (hide ~200-400cy L2 latency under QK+softmax);
//      the ds_write happens at the top of the next iteration, after
//      barrier2's vmcnt(0) has already drained them for free. +36 VGPR,
//      still 2 waves/SIMD.
//  (b) T13 defer-max (THR=8): skip the 128-mult O-rescale + alpha exp
//      unless the running max grew by >8. P bounded by e^8 -- safe in
//      bf16/f32, relative precision unchanged.
// V-tile [512][32] via global_load_lds issued EARLY (hidden behind QK) with
// XOR-swizzled source (4-way instead of 8-way bank conflicts on PV reads).
// ---------------------------------------------------------------------------
__device__ __forceinline__ short8 quad_transpose(unsigned d0, unsigned d1,
                                                 unsigned d2, unsigned d3,
                                                 int srcA, int srcB, bool lowquad)
{
    int e0 = __shfl((int)d0, srcA, 64);
    int e1 = __shfl((int)d1, srcA, 64);
    int e2 = __shfl((int)d2, srcA, 64);
    int e3 = __shfl((int)d3, srcA, 64);
    int f0 = __shfl((int)d0, srcB, 64);
    int f1 = __shfl((int)d1, srcB, 64);
    int f2 = __shfl((int)d2, srcB, 64);
    int f3 = __shfl((int)d3, srcB, 64);
    i4s8 u;
    u.i.x = lowquad ? e0 : e2;
    u.i.y = lowquad ? e1 : e3;
    u.i.z = lowquad ? f0 : f2;
    u.i.w = lowquad ? f1 : f3;
    return u.s;
}

__global__ __launch_bounds__(256, 2) void flash_attn4(
    const unsigned short* __restrict__ q_cat,
    const unsigned short* __restrict__ k_cat,
    const unsigned short* __restrict__ vt,
    const unsigned short* __restrict__ w2bf,
    unsigned short* __restrict__ attn_bf)
{
    __shared__ unsigned short sK[32*584];    // 37376 B, conflict-balanced stride
    __shared__ unsigned short sV[512*32];    // 32768 B, XOR-swizzled contents

    const int t    = threadIdx.x;
    const int wv   = t >> 6;
    const int lane = t & 63;
    const int lq   = lane & 15;
    const int quad = lane >> 4;
    const int h    = blockIdx.x;
    const int q0   = (31 - blockIdx.y) * 64;   // longest strips first
    const int b    = blockIdx.z;
    const int srcA = lq + ((quad & 1) << 5);
    const int srcB = srcA + 16;
    const bool lowq = quad < 2;
    const int myq  = q0 + wv*16 + lq;

    // Q fragments (loop-invariant)
    const unsigned short* qrow =
        q_cat + (((size_t)(b*NH_ + h)) * S_ + q0 + wv*16 + lq) * DTOT_ + quad*8;
    short8 qf[18];
#pragma unroll
    for (int c = 0; c < 18; ++c) qf[c] = *(const short8*)(qrow + c*32);

    const unsigned short* kcb = k_cat + (size_t)b * S_ * DTOT_;
    const unsigned short* vtb = vt    + (size_t)b * RANK_ * S_;

    f32x4 o[32];
#pragma unroll
    for (int i = 0; i < 32; ++i) o[i] = (f32x4){0.f, 0.f, 0.f, 0.f};
    float m_i = -1e30f, l_i = 0.f;
    const float scale = 0.0721687836f;  // 1/sqrt(192)
    const int ntiles = (q0 >> 5) + 2;

    // staging coords
    const int krow = t >> 3;                       // 0..31
    const int kcol = (t & 7) * 8;                  // shorts
    const int vrow = wv*16 + (lane >> 2);          // + p*64
    const int vgcol = (((lane & 3) ^ ((lane >> 2) & 3))) * 8;  // XOR-swizzled group
    const int pvsw = (quad ^ (lq & 3)) * 8;        // PV read group
    unsigned short* ldsK = &sK[krow*584 + kcol];

    // prologue: K(0) -> regs
    const unsigned short* kptr = kcb + (size_t)krow * DTOT_ + kcol;
    short8 kreg[9];
#pragma unroll
    for (int p = 0; p < 9; ++p) kreg[p] = *(const short8*)(kptr + p*64);
    kptr += 32 * DTOT_;

    for (int tt = 0; tt < ntiles; ++tt) {
        const int k0 = tt << 5;
        {   // K write: regs (drained by barrier2(t-1)'s vmcnt(0)) -> LDS.
            // sK free: every wave's QK(t-1) reads completed before barrier2.
#pragma unroll
            for (int p = 0; p < 9; ++p)
                *(short8*)(ldsK + p*64) = kreg[p];
        }
        __syncthreads();   // barrier1: K visible; Vbuf free (all PV(t-1) done)
        {   // V stage: issue DMA EARLY — latency hidden behind QK+softmax
#pragma unroll
            for (int p = 0; p < 8; ++p) {
                const unsigned short* vsrc =
                    vtb + (size_t)(p*64 + vrow) * S_ + k0 + vgcol;
                async_copy16(vsrc, &sV[p*2048 + wv*512]);
            }
        }
        // K(t+1) prefetch into regs — rides under QK+softmax+PV
        if (tt + 1 < ntiles) {
#pragma unroll
            for (int p = 0; p < 9; ++p) kreg[p] = *(const short8*)(kptr + p*64);
            kptr += 32 * DTOT_;
        }
        // QK^T
        f32x4 s0a = {0.f,0.f,0.f,0.f}, s0b = {0.f,0.f,0.f,0.f};
        f32x4 s1a = {0.f,0.f,0.f,0.f}, s1b = {0.f,0.f,0.f,0.f};
#pragma unroll
        for (int c = 0; c < 18; c += 2) {
            short8 ka0 = *(const short8*)&sK[lq*584      + c*32     + quad*8];
            short8 kb0 = *(const short8*)&sK[lq*584      + (c+1)*32 + quad*8];
            short8 ka1 = *(const short8*)&sK[(16+lq)*584 + c*32     + quad*8];
            short8 kb1 = *(const short8*)&sK[(16+lq)*584 + (c+1)*32 + quad*8];
            s0a = __builtin_amdgcn_mfma_f32_16x16x32_bf16(ka0, qf[c],   s0a, 0, 0, 0);
            s1a = __builtin_amdgcn_mfma_f32_16x16x32_bf16(ka1, qf[c],   s1a, 0, 0, 0);
            s0b = __builtin_amdgcn_mfma_f32_16x16x32_bf16(kb0, qf[c+1], s0b, 0, 0, 0);
            s1b = __builtin_amdgcn_mfma_f32_16x16x32_bf16(kb1, qf[c+1], s1b, 0, 0, 0);
        }
        // online softmax (per-lane q-row = myq), T13 defer-max THR=8
        float sv[8];
#pragma unroll
        for (int r = 0; r < 4; ++r) {
            int kk0 = k0 + quad*4 + r;
            sv[r]     = (kk0      <= myq) ? (s0a[r] + s0b[r]) * scale : -1e30f;
            sv[r + 4] = (kk0 + 16 <= myq) ? (s1a[r] + s1b[r]) * scale : -1e30f;
        }
        float mx = sv[0];
#pragma unroll
        for (int i = 1; i < 8; ++i) mx = fmaxf(mx, sv[i]);
        mx = fmaxf(mx, __shfl_xor(mx, 16));
        mx = fmaxf(mx, __shfl_xor(mx, 32));
        if (!__all(mx <= m_i + 8.f)) {     // wave-uniform branch, rare after warmup
            const float m_new = fmaxf(m_i, mx);
            const float alpha = __expf(m_i - m_new);
            m_i = m_new;
            l_i *= alpha;
#pragma unroll
            for (int i = 0; i < 32; ++i) {
                o[i][0]*=alpha; o[i][1]*=alpha; o[i][2]*=alpha; o[i][3]*=alpha;
            }
        }
        float p[8]; float ls = 0.f;
#pragma unroll
        for (int i = 0; i < 8; ++i) { p[i] = __expf(sv[i] - m_i); ls += p[i]; }
        ls += __shfl_xor(ls, 16);
        ls += __shfl_xor(ls, 32);
        l_i += ls;
        short8 pb = quad_transpose(pack2bf(p[0], p[1]), pack2bf(p[2], p[3]),
                                   pack2bf(p[4], p[5]), pack2bf(p[6], p[7]),
                                   srcA, srcB, lowq);
        __syncthreads();   // barrier2: drains V DMA + K prefetch; K-tile reads complete
        // PV (swizzled reads: 4-way max conflict)
#pragma unroll
        for (int ct = 0; ct < 32; ++ct) {
            short8 va = *(const short8*)&sV[(ct*16 + lq)*32 + pvsw];
            o[ct] = __builtin_amdgcn_mfma_f32_16x16x32_bf16(va, pb, o[ct], 0, 0, 0);
        }
    }

    // epilogue: X @ out_absorb^T, bf16 out
    const float inv = 1.0f / l_i;
    f32x4 acc[8];
#pragma unroll
    for (int i = 0; i < 8; ++i) acc[i] = (f32x4){0.f, 0.f, 0.f, 0.f};
    const unsigned short* wrow = w2bf + ((size_t)h*256 + NOPE_ + lq) * RANK_ + quad*8;
#pragma unroll
    for (int ch = 0; ch < 16; ++ch) {
        short8 xa = quad_transpose(
            pack2bf(o[2*ch][0]*inv,   o[2*ch][1]*inv),
            pack2bf(o[2*ch][2]*inv,   o[2*ch][3]*inv),
            pack2bf(o[2*ch+1][0]*inv, o[2*ch+1][1]*inv),
            pack2bf(o[2*ch+1][2]*inv, o[2*ch+1][3]*inv),
            srcA, srcB, lowq);
#pragma unroll
        for (int dt = 0; dt < 8; ++dt) {
            short8 wf = *(const short8*)(wrow + (size_t)dt*16*RANK_ + ch*32);
            acc[dt] = __builtin_amdgcn_mfma_f32_16x16x32_bf16(xa, wf, acc[dt], 0, 0, 0);
        }
    }
    unsigned short* orow =
        attn_bf + ((size_t)b * S_ + q0 + wv*16 + quad*4) * (NH_*VDIM_) + h*VDIM_ + lq;
#pragma unroll
    for (int dt = 0; dt < 8; ++dt)
#pragma unroll
        for (int r = 0; r < 4; ++r)
            orow[(size_t)r * (NH_*VDIM_) + dt*16] = f2bf(acc[dt][r]);
}

extern "C" void kernel_launch(void* const* d_in, const int* in_sizes, int n_in,
                              void* d_out, int out_size, void* d_ws, size_t ws_size,
                              hipStream_t stream)
{
    const float* hidden  = (const float*)d_in[0];
    // d_in[1] = attention_mask (guaranteed causal tril, handled analytically)
    const int*   pos_ids = (const int*)d_in[2];
    const float* cosc    = (const float*)d_in[3];
    const float* sinc    = (const float*)d_in[4];
    const float* Wq      = (const float*)d_in[5];
    const float* Wkv_a   = (const float*)d_in[6];
    const float* lnw     = (const float*)d_in[7];
    const float* Wkv_b   = (const float*)d_in[8];
    const float* Wo      = (const float*)d_in[9];
    float* out = (float*)d_out;

    const int M = B_ * S_;  // 4096
    char* ws = (char*)d_ws;
    // Workspace layout (139.5 MB total, time-disjoint aliases):
    unsigned short* hidden_bf = (unsigned short*)ws;                 // 16.78 MB (live 1-5)
    unsigned short* wqaT      = (unsigned short*)ws;                 // alias (live 10-11)
    unsigned short* attn_bf   = (unsigned short*)ws;                 // alias (live 12-14)
    unsigned short* q_bf      = (unsigned short*)(ws + 16777216);    // 25.17 MB (live 3-11)
    unsigned short* ckv_bf    = (unsigned short*)(ws + 41943040);    // 4.72 MB (live 5-6)
    unsigned short* vt        = ckv_bf;                              // alias (live 8-12)
    unsigned short* q_cat     = (unsigned short*)(ws + 46661632);    // 75.50 MB (live 7-12)
    unsigned short* k_cat     = (unsigned short*)(ws + 122159104);   // 4.72 MB (live 6-12)
    unsigned short* wT        = (unsigned short*)(ws + 126877696);   // 12.58 MB (WqT/WkvaT/WoT)
    unsigned short* w2bf      = (unsigned short*)(ws + 126877696 + 8388608); // 4.19 MB (live 9-12)

    // 1. hidden -> bf16
    cast_bf16<<<8192, 256, 0, stream>>>(hidden, hidden_bf);
    // 2. WqT = Wq^T bf16 [3072][2048]
    transpose_w<<<dim3(32, 48, 1), 256, 0, stream>>>(Wq, wT, H_, NH_*QHD_, 0, 0);
    // 3. q_bf = hidden @ Wq (bf16 out)
    bgemm2<<<dim3(24, 32, 1), 256, 0, stream>>>(hidden_bf, H_, wT, q_bf, NH_*QHD_, H_, NH_*QHD_, 0);
    // 4. WkvaT bf16 [576][2048]
    transpose_w<<<dim3(32, 9, 1), 256, 0, stream>>>(Wkv_a, wT, H_, DTOT_, 0, 0);
    // 5. ckv_bf = hidden @ Wkv_a (bf16 out, ragged N=576)
    bgemm2<<<dim3(5, 32, 1), 256, 0, stream>>>(hidden_bf, H_, wT, ckv_bf, DTOT_, H_, DTOT_, 0);
    // 6. RMSNorm + k_pe RoPE -> k_cat
    postkv<<<M, 128, 0, stream>>>(ckv_bf, lnw, pos_ids, cosc, sinc, k_cat);
    // 7. q_pe RoPE -> q_cat[...,512:576]
    ropeq<<<M, 512, 0, stream>>>(q_bf, pos_ids, cosc, sinc, q_cat);
    // 8. Vt = transpose of k_cat[:, :512]
    transpose_v<<<dim3(S_/64, RANK_/64, B_), 256, 0, stream>>>(k_cat, vt);
    // 9. Wkv_b -> bf16 (flash epilogue weights)
    wcast<<<(NH_*256*RANK_)/1024, 256, 0, stream>>>(Wkv_b, w2bf);
    // 10. wqaT[h] = (Wkv_b[h][0:128])^T bf16 [512][128]
    transpose_w<<<dim3(2, 8, 16), 256, 0, stream>>>(Wkv_b, wqaT, NOPE_, RANK_,
                                                    (size_t)256*RANK_, (size_t)RANK_*NOPE_);
    // 11. q_cat[...,0:512] = q_nope @ q_absorb (batched, K=128)
    bgemm2<<<dim3(4, 16, 32), 256, 0, stream>>>(q_bf, NH_*QHD_, wqaT, q_cat, DTOT_, NOPE_, RANK_, 1);
    // 12. flash attention -> attn_bf (bf16)
    flash_attn4<<<dim3(NH_, S_/64, B_), 256, 0, stream>>>(q_cat, k_cat, vt, w2bf, attn_bf);
    // 13. WoT bf16 [2048][2048]
    transpose_w<<<dim3(32, 32, 1), 256, 0, stream>>>(Wo, wT, H_, H_, 0, 0);
    // 14. out = attn @ Wo (f32 out)
    bgemm2f<<<dim3(16, 32, 1), 256, 0, stream>>>(attn_bf, H_, wT, out, H_, H_, H_);
}

// Round 2
// 789.506 us; speedup vs baseline: 1.1966x; 1.1966x over previous
//
#include <hip/hip_runtime.h>
#include <math.h>

#define B_    2
#define S_    2048
#define H_    2048
#define NH_   16
#define NOPE_ 128
#define ROPE_ 64
#define VDIM_ 128
#define RANK_ 512
#define QHD_  192   // NOPE + ROPE
#define DTOT_ 576   // RANK + ROPE

typedef short short8 __attribute__((ext_vector_type(8)));
typedef float f32x4 __attribute__((ext_vector_type(4)));

__device__ __forceinline__ unsigned short f2bf(float f) {
    unsigned u = __float_as_uint(f);
    u += 0x7fffu + ((u >> 16) & 1u);
    return (unsigned short)(u >> 16);
}
__device__ __forceinline__ float bf2f(unsigned short u) {
    return __uint_as_float((unsigned)u << 16);
}
__device__ __forceinline__ unsigned pack2bf(float a, float b) {
    return (unsigned)f2bf(a) | ((unsigned)f2bf(b) << 16);
}
__device__ __forceinline__ unsigned long long pack4bf(float a, float b, float c, float d) {
    return (unsigned long long)pack2bf(a, b) | ((unsigned long long)pack2bf(c, d) << 32);
}
union i4s8 { int4 i; short8 s; };

// Async global->LDS, 16B per lane. LDS dest = wave-uniform base + lane*16.
typedef __attribute__((address_space(3))) unsigned int lds_u32_t;
typedef __attribute__((address_space(1))) const unsigned int glob_u32_t;
__device__ __forceinline__ void async_copy16(const unsigned short* g, unsigned short* l) {
    __builtin_amdgcn_global_load_lds((glob_u32_t*)g, (lds_u32_t*)l, 16, 0, 0);
}

// ---------------------------------------------------------------------------
// cast fp32 -> bf16, 4 elems/thread.
// ---------------------------------------------------------------------------
__global__ __launch_bounds__(256) void cast_bf16(const float* __restrict__ in,
                                                 unsigned short* __restrict__ out)
{
    const size_t i = ((size_t)blockIdx.x * 256 + threadIdx.x) * 4;
    float4 v = *(const float4*)(in + i);
    *(unsigned long long*)(out + i) = pack4bf(v.x, v.y, v.z, v.w);
}

// ---------------------------------------------------------------------------
// Transpose + cast: in fp32 [Rr][Cc] (batched) -> out bf16 [Cc][Rr].
// grid (Rr/64, Cc/64, batch), 256 threads.
// ---------------------------------------------------------------------------
__global__ __launch_bounds__(256) void transpose_w(const float* __restrict__ in,
                                                   unsigned short* __restrict__ out,
                                                   int Rr, int Cc,
                                                   size_t inBatch, size_t outBatch)
{
    __shared__ unsigned short tl[64][72];
    in  += (size_t)blockIdx.z * inBatch;
    out += (size_t)blockIdx.z * outBatch;
    const int t  = threadIdx.x;
    const int r0 = blockIdx.x * 64;
    const int c0 = blockIdx.y * 64;
    const int lr = t >> 4;
    const int lc = (t & 15) * 4;
#pragma unroll
    for (int r = 0; r < 4; ++r) {
        float4 v = *(const float4*)(in + (size_t)(r0 + lr*4 + r) * Cc + c0 + lc);
        tl[lr*4 + r][lc+0] = f2bf(v.x); tl[lr*4 + r][lc+1] = f2bf(v.y);
        tl[lr*4 + r][lc+2] = f2bf(v.z); tl[lr*4 + r][lc+3] = f2bf(v.w);
    }
    __syncthreads();
#pragma unroll
    for (int r = 0; r < 4; ++r) {
        ushort4 v;
        v.x = tl[lc+0][lr*4+r]; v.y = tl[lc+1][lr*4+r];
        v.z = tl[lc+2][lr*4+r]; v.w = tl[lc+3][lr*4+r];
        *(ushort4*)(out + (size_t)(c0 + lr*4 + r) * Rr + r0 + lc) = v;
    }
}

// ---------------------------------------------------------------------------
// bf16 MFMA GEMM, m97-style: C = A[M][K](lda) @ Bt^T, Bt bf16 [N][K].
// 128x128 tile, 4 waves, BK=32, global_load_lds staging. N-guard for ragged N.
// ---------------------------------------------------------------------------
#define BGEMM_BODY(STORE_STMT)                                                     \
    __shared__ unsigned short Al[128*32];                                          \
    __shared__ unsigned short Bl[128*32];                                          \
    const int t = threadIdx.x;                                                     \
    const int wv = t >> 6;                                                         \
    const int lane = t & 63;                                                       \
    const int lq = lane & 15, quad = lane >> 4;                                    \
    const int m0 = blockIdx.y * 128, n0 = blockIdx.x * 128;                        \
    const int wrow = (wv >> 1) * 64, wcol = (wv & 1) * 64;                         \
    const int srow = lane >> 2;                                                    \
    const int scol = (lane & 3) * 8;                                               \
    f32x4 acc[4][4] = {};                                                          \
    for (int k0 = 0; k0 < K; k0 += 32) {                                           \
        _Pragma("unroll")                                                          \
        for (int pA = 0; pA < 2; ++pA) {                                           \
            const unsigned short* src =                                            \
                A + (size_t)(m0 + pA*64 + wv*16 + srow) * lda + k0 + scol;         \
            async_copy16(src, &Al[pA*2048 + wv*512]);                              \
        }                                                                          \
        _Pragma("unroll")                                                          \
        for (int pB = 0; pB < 2; ++pB) {                                           \
            int brow = n0 + pB*64 + wv*16 + srow;                                  \
            if (brow > N - 1) brow = N - 1;                                        \
            const unsigned short* src = B + (size_t)brow * K + k0 + scol;          \
            async_copy16(src, &Bl[pB*2048 + wv*512]);                              \
        }                                                                          \
        __syncthreads();                                                           \
        short8 af[4], bf[4];                                                       \
        _Pragma("unroll")                                                          \
        for (int i = 0; i < 4; ++i) {                                              \
            af[i] = *(const short8*)&Al[(wrow + i*16 + lq)*32 + quad*8];           \
            bf[i] = *(const short8*)&Bl[(wcol + i*16 + lq)*32 + quad*8];           \
        }                                                                          \
        _Pragma("unroll")                                                          \
        for (int mi = 0; mi < 4; ++mi)                                             \
            _Pragma("unroll")                                                      \
            for (int ni = 0; ni < 4; ++ni)                                         \
                acc[mi][ni] = __builtin_amdgcn_mfma_f32_16x16x32_bf16(             \
                    af[mi], bf[ni], acc[mi][ni], 0, 0, 0);                         \
        __syncthreads();                                                           \
    }                                                                              \
    _Pragma("unroll")                                                              \
    for (int mi = 0; mi < 4; ++mi)                                                 \
        _Pragma("unroll")                                                          \
        for (int ni = 0; ni < 4; ++ni) {                                           \
            int col = n0 + wcol + ni*16 + lq;                                      \
            if (col < N) {                                                         \
                _Pragma("unroll")                                                  \
                for (int r = 0; r < 4; ++r)                                        \
                    STORE_STMT;                                                    \
            }                                                                      \
        }

__global__ __launch_bounds__(256, 2) void bgemm2(const unsigned short* __restrict__ A,
                                                 int lda,
                                                 const unsigned short* __restrict__ B,
                                                 unsigned short* __restrict__ C,
                                                 int ldc, int K, int N, int qcmode)
{
    if (qcmode) {
        const int z = blockIdx.z;
        A += (size_t)(z >> 4) * S_ * (NH_*QHD_) + (z & 15) * QHD_;
        B += (size_t)(z & 15) * RANK_ * NOPE_;
        C += (size_t)z * S_ * DTOT_;
    }
    BGEMM_BODY(C[(size_t)(m0 + wrow + mi*16 + quad*4 + r) * ldc + col] = f2bf(acc[mi][ni][r]))
}

__global__ __launch_bounds__(256, 2) void bgemm2f(const unsigned short* __restrict__ A,
                                                  int lda,
                                                  const unsigned short* __restrict__ B,
                                                  float* __restrict__ C,
                                                  int ldc, int K, int N)
{
    BGEMM_BODY(C[(size_t)(m0 + wrow + mi*16 + quad*4 + r) * ldc + col] = acc[mi][ni][r])
}

// ---------------------------------------------------------------------------
// Per (b,s) row: RMSNorm ckv (bf16 in) -> k_cat[0:512]; RoPE k_pe -> [512:576].
// ---------------------------------------------------------------------------
__global__ __launch_bounds__(128) void postkv(const unsigned short* __restrict__ ckv_bf,
                                              const float* __restrict__ lnw,
                                              const int*   __restrict__ pos_ids,
                                              const float* __restrict__ cosc,
                                              const float* __restrict__ sinc,
                                              unsigned short* __restrict__ k_cat)
{
    const int row = blockIdx.x;
    const int t   = threadIdx.x;
    const unsigned short* src = ckv_bf + (size_t)row * DTOT_;
    __shared__ float red[128];

    ushort4 v = *(const ushort4*)(src + t * 4);
    float x0 = bf2f(v.x), x1 = bf2f(v.y), x2 = bf2f(v.z), x3 = bf2f(v.w);
    red[t] = x0*x0 + x1*x1 + x2*x2 + x3*x3;
    __syncthreads();
    for (int off = 64; off > 0; off >>= 1) {
        if (t < off) red[t] += red[t + off];
        __syncthreads();
    }
    const float rs = rsqrtf(red[0] / (float)RANK_ + 1e-6f);

    unsigned short* kc = k_cat + (size_t)row * DTOT_;
    *(unsigned long long*)(kc + t*4) =
        pack4bf(x0*rs*lnw[t*4+0], x1*rs*lnw[t*4+1], x2*rs*lnw[t*4+2], x3*rs*lnw[t*4+3]);

    if (t < 32) {
        const int pos = pos_ids[row];
        const float c  = cosc[pos * ROPE_ + t];
        const float sn = sinc[pos * ROPE_ + t];
        const float y0 = bf2f(src[RANK_ + 2*t]);
        const float y1 = bf2f(src[RANK_ + 2*t + 1]);
        kc[RANK_ + t]      = f2bf(y0*c - y1*sn);
        kc[RANK_ + 32 + t] = f2bf(y1*c + y0*sn);
    }
}

// ---------------------------------------------------------------------------
// RoPE q_pe (bf16 in) -> q_cat[...,512:576]. grid = B*S, 512 threads.
// ---------------------------------------------------------------------------
__global__ __launch_bounds__(512) void ropeq(const unsigned short* __restrict__ q_bf,
                                             const int*   __restrict__ pos_ids,
                                             const float* __restrict__ cosc,
                                             const float* __restrict__ sinc,
                                             unsigned short* __restrict__ q_cat)
{
    const int row = blockIdx.x;
    const int t   = threadIdx.x;
    const int h   = t >> 5;
    const int i   = t & 31;
    const int pos = pos_ids[row];
    const float c  = cosc[pos * ROPE_ + i];
    const float sn = sinc[pos * ROPE_ + i];
    const unsigned short* qrow = q_bf + (size_t)row * (NH_*QHD_) + h * QHD_ + NOPE_;
    const float x0 = bf2f(qrow[2*i]);
    const float x1 = bf2f(qrow[2*i + 1]);
    const int b = row >> 11, s = row & 2047;
    unsigned short* qc = q_cat + ((size_t)(b * NH_ + h) * S_ + s) * DTOT_ + RANK_;
    qc[i]      = f2bf(x0*c - x1*sn);
    qc[32 + i] = f2bf(x1*c + x0*sn);
}

// ---------------------------------------------------------------------------
// Vt[b,c,k] = k_cat[b,k,c] for c<512. grid (32, 8, 2).
// ---------------------------------------------------------------------------
__global__ __launch_bounds__(256) void transpose_v(const unsigned short* __restrict__ k_cat,
                                                   unsigned short* __restrict__ vt)
{
    __shared__ unsigned short tl[64][72];
    const int t  = threadIdx.x;
    const int k0 = blockIdx.x * 64;
    const int c0 = blockIdx.y * 64;
    const int b  = blockIdx.z;
    const int lr = t >> 4;
    const int lc = (t & 15) * 4;
#pragma unroll
    for (int r = 0; r < 4; ++r) {
        ushort4 v = *(const ushort4*)(k_cat + ((size_t)b * S_ + k0 + lr*4 + r) * DTOT_ + c0 + lc);
        tl[lr*4 + r][lc+0] = v.x; tl[lr*4 + r][lc+1] = v.y;
        tl[lr*4 + r][lc+2] = v.z; tl[lr*4 + r][lc+3] = v.w;
    }
    __syncthreads();
#pragma unroll
    for (int r = 0; r < 4; ++r) {
        ushort4 v;
        v.x = tl[lc+0][lr*4+r]; v.y = tl[lc+1][lr*4+r];
        v.z = tl[lc+2][lr*4+r]; v.w = tl[lc+3][lr*4+r];
        *(ushort4*)(vt + ((size_t)b * RANK_ + c0 + lr*4 + r) * S_ + k0 + lc) = v;
    }
}

__global__ __launch_bounds__(256) void wcast(const float* __restrict__ w,
                                             unsigned short* __restrict__ wbf)
{
    const size_t i = ((size_t)blockIdx.x * 256 + threadIdx.x) * 4;
    float4 v = *(const float4*)(w + i);
    *(unsigned long long*)(wbf + i) = pack4bf(v.x, v.y, v.z, v.w);
}

// ---------------------------------------------------------------------------
// Flash attention v6: 4 waves/block, 64 q-rows, 2 barriers/tile.
// Both K and V staged via global_load_lds DMA (zero register cost — the v5
// register-staged K prefetch spilled to scratch at the 128-VGPR cap:
// WRITE_SIZE 16MB->700MB; this keeps the async-split idea without registers).
//  - K tile (32 contiguous rows of k_cat, 36864B) -> linear sK with
//    XOR-swizzled SOURCE granules (gc ^ (row&7)); QK reads apply the same
//    XOR via per-lane base + compile-time offsets => conflict-free b128.
//  - K(t+1) DMA issued right after barrier2, latency hidden under PV and
//    drained by next iteration's barrier1 (cross-back-edge pipeline).
//  - V DMA issued after barrier1, hidden under QK+softmax (as before).
//  - T13 defer-max (THR=8): skip O-rescale unless running max grows >8.
// ---------------------------------------------------------------------------
__device__ __forceinline__ short8 quad_transpose(unsigned d0, unsigned d1,
                                                 unsigned d2, unsigned d3,
                                                 int srcA, int srcB, bool lowquad)
{
    int e0 = __shfl((int)d0, srcA, 64);
    int e1 = __shfl((int)d1, srcA, 64);
    int e2 = __shfl((int)d2, srcA, 64);
    int e3 = __shfl((int)d3, srcA, 64);
    int f0 = __shfl((int)d0, srcB, 64);
    int f1 = __shfl((int)d1, srcB, 64);
    int f2 = __shfl((int)d2, srcB, 64);
    int f3 = __shfl((int)d3, srcB, 64);
    i4s8 u;
    u.i.x = lowquad ? e0 : e2;
    u.i.y = lowquad ? e1 : e3;
    u.i.z = lowquad ? f0 : f2;
    u.i.w = lowquad ? f1 : f3;
    return u.s;
}

__global__ __launch_bounds__(256, 2) void flash_attn4(
    const unsigned short* __restrict__ q_cat,
    const unsigned short* __restrict__ k_cat,
    const unsigned short* __restrict__ vt,
    const unsigned short* __restrict__ w2bf,
    unsigned short* __restrict__ attn_bf)
{
    __shared__ unsigned short sK[32*576];    // 36864 B, linear dest, swizzled contents
    __shared__ unsigned short sV[512*32];    // 32768 B, XOR-swizzled contents

    const int t    = threadIdx.x;
    const int wv   = t >> 6;
    const int lane = t & 63;
    const int lq   = lane & 15;
    const int quad = lane >> 4;
    const int h    = blockIdx.x;
    const int q0   = (31 - blockIdx.y) * 64;   // longest strips first
    const int b    = blockIdx.z;
    const int srcA = lq + ((quad & 1) << 5);
    const int srcB = srcA + 16;
    const bool lowq = quad < 2;
    const int myq  = q0 + wv*16 + lq;

    // Q fragments (loop-invariant)
    const unsigned short* qrow =
        q_cat + (((size_t)(b*NH_ + h)) * S_ + q0 + wv*16 + lq) * DTOT_ + quad*8;
    short8 qf[18];
#pragma unroll
    for (int c = 0; c < 18; ++c) qf[c] = *(const short8*)(qrow + c*32);

    const unsigned short* kcb = k_cat + (size_t)b * S_ * DTOT_;
    const unsigned short* vtb = vt    + (size_t)b * RANK_ * S_;

    f32x4 o[32];
#pragma unroll
    for (int i = 0; i < 32; ++i) o[i] = (f32x4){0.f, 0.f, 0.f, 0.f};
    float m_i = -1e30f, l_i = 0.f;
    const float scale = 0.0721687836f;  // 1/sqrt(192)
    const int ntiles = (q0 >> 5) + 2;

    // --- K read-side swizzle: logical granule (row lq, 4c+quad) lives at
    // physical granule (4c+quad)^(lq&7) = (quad^(swz&3)) + 4*(c^(swz>>2)).
    const int swz  = lq & 7;
    const int selA = (swz >> 2) * 32;           // shorts: +32 if bit2 of swz
    const int selB = 32 - selA;
    const int kqo  = (quad ^ (swz & 3)) * 8;    // shorts within 128B block
    const unsigned short* kr0 = &sK[lq*576 + kqo];
    const unsigned short* kr1 = &sK[(16 + lq)*576 + kqo];

    // V staging coords (unchanged)
    const int vrow  = wv*16 + (lane >> 2);                       // + p*64
    const int vgcol = (((lane & 3) ^ ((lane >> 2) & 3))) * 8;    // XOR-swizzled group
    const int pvsw  = (quad ^ (lq & 3)) * 8;                     // PV read group

    // K DMA: granule G = p*256 + t of the linear 2304-granule tile;
    // source granule (row = G/72) column gc^(row&7). Per-lane source addr,
    // wave-uniform LDS dest (HW adds lane*16).
#define ISSUE_K(TPTR)                                                          \
    _Pragma("unroll")                                                          \
    for (int p = 0; p < 9; ++p) {                                              \
        const int G  = p*256 + t;                                              \
        const int kr = G / 72;                                                 \
        const int gc = G - kr*72;                                              \
        async_copy16((TPTR) + kr*DTOT_ + ((gc ^ (kr & 7)) << 3),               \
                     &sK[p*2048 + wv*512]);                                    \
    }

    const unsigned short* ktp = kcb;      // K tile pointer, +32*DTOT_ per tile
    ISSUE_K(ktp);
    ktp += 32 * DTOT_;

    for (int tt = 0; tt < ntiles; ++tt) {
        const int k0 = tt << 5;
        __syncthreads();   // barrier1: K(tt) DMA drained -> sK valid; sV free
        {   // V stage: issue DMA EARLY — latency hidden behind QK+softmax
#pragma unroll
            for (int p = 0; p < 8; ++p) {
                const unsigned short* vsrc =
                    vtb + (size_t)(p*64 + vrow) * S_ + k0 + vgcol;
                async_copy16(vsrc, &sV[p*2048 + wv*512]);
            }
        }
        // QK^T (swizzled reads: per-lane base + compile-time offsets)
        f32x4 s0a = {0.f,0.f,0.f,0.f}, s0b = {0.f,0.f,0.f,0.f};
        f32x4 s1a = {0.f,0.f,0.f,0.f}, s1b = {0.f,0.f,0.f,0.f};
#pragma unroll
        for (int c = 0; c < 18; c += 2) {
            short8 ka0 = *(const short8*)(kr0 + c*32 + selA);
            short8 kb0 = *(const short8*)(kr0 + c*32 + selB);
            short8 ka1 = *(const short8*)(kr1 + c*32 + selA);
            short8 kb1 = *(const short8*)(kr1 + c*32 + selB);
            s0a = __builtin_amdgcn_mfma_f32_16x16x32_bf16(ka0, qf[c],   s0a, 0, 0, 0);
            s1a = __builtin_amdgcn_mfma_f32_16x16x32_bf16(ka1, qf[c],   s1a, 0, 0, 0);
            s0b = __builtin_amdgcn_mfma_f32_16x16x32_bf16(kb0, qf[c+1], s0b, 0, 0, 0);
            s1b = __builtin_amdgcn_mfma_f32_16x16x32_bf16(kb1, qf[c+1], s1b, 0, 0, 0);
        }
        // online softmax (per-lane q-row = myq), T13 defer-max THR=8
        float sv[8];
#pragma unroll
        for (int r = 0; r < 4; ++r) {
            int kk0 = k0 + quad*4 + r;
            sv[r]     = (kk0      <= myq) ? (s0a[r] + s0b[r]) * scale : -1e30f;
            sv[r + 4] = (kk0 + 16 <= myq) ? (s1a[r] + s1b[r]) * scale : -1e30f;
        }
        float mx = sv[0];
#pragma unroll
        for (int i = 1; i < 8; ++i) mx = fmaxf(mx, sv[i]);
        mx = fmaxf(mx, __shfl_xor(mx, 16));
        mx = fmaxf(mx, __shfl_xor(mx, 32));
        if (!__all(mx <= m_i + 8.f)) {     // wave-uniform branch, rare after warmup
            const float m_new = fmaxf(m_i, mx);
            const float alpha = __expf(m_i - m_new);
            m_i = m_new;
            l_i *= alpha;
#pragma unroll
            for (int i = 0; i < 32; ++i) {
                o[i][0]*=alpha; o[i][1]*=alpha; o[i][2]*=alpha; o[i][3]*=alpha;
            }
        }
        float p[8]; float ls = 0.f;
#pragma unroll
        for (int i = 0; i < 8; ++i) { p[i] = __expf(sv[i] - m_i); ls += p[i]; }
        ls += __shfl_xor(ls, 16);
        ls += __shfl_xor(ls, 32);
        l_i += ls;
        short8 pb = quad_transpose(pack2bf(p[0], p[1]), pack2bf(p[2], p[3]),
                                   pack2bf(p[4], p[5]), pack2bf(p[6], p[7]),
                                   srcA, srcB, lowq);
        __syncthreads();   // barrier2: V(tt) DMA drained; all QK reads of sK done
        // K(t+1) DMA: issued now, hidden under PV, drained at next barrier1
        if (tt + 1 < ntiles) {
            ISSUE_K(ktp);
            ktp += 32 * DTOT_;
        }
        // PV (swizzled reads: 4-way max conflict)
#pragma unroll
        for (int ct = 0; ct < 32; ++ct) {
            short8 va = *(const short8*)&sV[(ct*16 + lq)*32 + pvsw];
            o[ct] = __builtin_amdgcn_mfma_f32_16x16x32_bf16(va, pb, o[ct], 0, 0, 0);
        }
    }

    // epilogue: X @ out_absorb^T, bf16 out
    const float inv = 1.0f / l_i;
    f32x4 acc[8];
#pragma unroll
    for (int i = 0; i < 8; ++i) acc[i] = (f32x4){0.f, 0.f, 0.f, 0.f};
    const unsigned short* wrow = w2bf + ((size_t)h*256 + NOPE_ + lq) * RANK_ + quad*8;
#pragma unroll
    for (int ch = 0; ch < 16; ++ch) {
        short8 xa = quad_transpose(
            pack2bf(o[2*ch][0]*inv,   o[2*ch][1]*inv),
            pack2bf(o[2*ch][2]*inv,   o[2*ch][3]*inv),
            pack2bf(o[2*ch+1][0]*inv, o[2*ch+1][1]*inv),
            pack2bf(o[2*ch+1][2]*inv, o[2*ch+1][3]*inv),
            srcA, srcB, lowq);
#pragma unroll
        for (int dt = 0; dt < 8; ++dt) {
            short8 wf = *(const short8*)(wrow + (size_t)dt*16*RANK_ + ch*32);
            acc[dt] = __builtin_amdgcn_mfma_f32_16x16x32_bf16(xa, wf, acc[dt], 0, 0, 0);
        }
    }
    unsigned short* orow =
        attn_bf + ((size_t)b * S_ + q0 + wv*16 + quad*4) * (NH_*VDIM_) + h*VDIM_ + lq;
#pragma unroll
    for (int dt = 0; dt < 8; ++dt)
#pragma unroll
        for (int r = 0; r < 4; ++r)
            orow[(size_t)r * (NH_*VDIM_) + dt*16] = f2bf(acc[dt][r]);
}

extern "C" void kernel_launch(void* const* d_in, const int* in_sizes, int n_in,
                              void* d_out, int out_size, void* d_ws, size_t ws_size,
                              hipStream_t stream)
{
    const float* hidden  = (const float*)d_in[0];
    // d_in[1] = attention_mask (guaranteed causal tril, handled analytically)
    const int*   pos_ids = (const int*)d_in[2];
    const float* cosc    = (const float*)d_in[3];
    const float* sinc    = (const float*)d_in[4];
    const float* Wq      = (const float*)d_in[5];
    const float* Wkv_a   = (const float*)d_in[6];
    const float* lnw     = (const float*)d_in[7];
    const float* Wkv_b   = (const float*)d_in[8];
    const float* Wo      = (const float*)d_in[9];
    float* out = (float*)d_out;

    const int M = B_ * S_;  // 4096
    char* ws = (char*)d_ws;
    // Workspace layout (139.5 MB total, time-disjoint aliases):
    unsigned short* hidden_bf = (unsigned short*)ws;                 // 16.78 MB (live 1-5)
    unsigned short* wqaT      = (unsigned short*)ws;                 // alias (live 10-11)
    unsigned short* attn_bf   = (unsigned short*)ws;                 // alias (live 12-14)
    unsigned short* q_bf      = (unsigned short*)(ws + 16777216);    // 25.17 MB (live 3-11)
    unsigned short* ckv_bf    = (unsigned short*)(ws + 41943040);    // 4.72 MB (live 5-6)
    unsigned short* vt        = ckv_bf;                              // alias (live 8-12)
    unsigned short* q_cat     = (unsigned short*)(ws + 46661632);    // 75.50 MB (live 7-12)
    unsigned short* k_cat     = (unsigned short*)(ws + 122159104);   // 4.72 MB (live 6-12)
    unsigned short* wT        = (unsigned short*)(ws + 126877696);   // 12.58 MB (WqT/WkvaT/WoT)
    unsigned short* w2bf      = (unsigned short*)(ws + 126877696 + 8388608); // 4.19 MB (live 9-12)

    // 1. hidden -> bf16
    cast_bf16<<<8192, 256, 0, stream>>>(hidden, hidden_bf);
    // 2. WqT = Wq^T bf16 [3072][2048]
    transpose_w<<<dim3(32, 48, 1), 256, 0, stream>>>(Wq, wT, H_, NH_*QHD_, 0, 0);
    // 3. q_bf = hidden @ Wq (bf16 out)
    bgemm2<<<dim3(24, 32, 1), 256, 0, stream>>>(hidden_bf, H_, wT, q_bf, NH_*QHD_, H_, NH_*QHD_, 0);
    // 4. WkvaT bf16 [576][2048]
    transpose_w<<<dim3(32, 9, 1), 256, 0, stream>>>(Wkv_a, wT, H_, DTOT_, 0, 0);
    // 5. ckv_bf = hidden @ Wkv_a (bf16 out, ragged N=576)
    bgemm2<<<dim3(5, 32, 1), 256, 0, stream>>>(hidden_bf, H_, wT, ckv_bf, DTOT_, H_, DTOT_, 0);
    // 6. RMSNorm + k_pe RoPE -> k_cat
    postkv<<<M, 128, 0, stream>>>(ckv_bf, lnw, pos_ids, cosc, sinc, k_cat);
    // 7. q_pe RoPE -> q_cat[...,512:576]
    ropeq<<<M, 512, 0, stream>>>(q_bf, pos_ids, cosc, sinc, q_cat);
    // 8. Vt = transpose of k_cat[:, :512]
    transpose_v<<<dim3(S_/64, RANK_/64, B_), 256, 0, stream>>>(k_cat, vt);
    // 9. Wkv_b -> bf16 (flash epilogue weights)
    wcast<<<(NH_*256*RANK_)/1024, 256, 0, stream>>>(Wkv_b, w2bf);
    // 10. wqaT[h] = (Wkv_b[h][0:128])^T bf16 [512][128]
    transpose_w<<<dim3(2, 8, 16), 256, 0, stream>>>(Wkv_b, wqaT, NOPE_, RANK_,
                                                    (size_t)256*RANK_, (size_t)RANK_*NOPE_);
    // 11. q_cat[...,0:512] = q_nope @ q_absorb (batched, K=128)
    bgemm2<<<dim3(4, 16, 32), 256, 0, stream>>>(q_bf, NH_*QHD_, wqaT, q_cat, DTOT_, NOPE_, RANK_, 1);
    // 12. flash attention -> attn_bf (bf16)
    flash_attn4<<<dim3(NH_, S_/64, B_), 256, 0, stream>>>(q_cat, k_cat, vt, w2bf, attn_bf);
    // 13. WoT bf16 [2048][2048]
    transpose_w<<<dim3(32, 32, 1), 256, 0, stream>>>(Wo, wT, H_, H_, 0, 0);
    // 14. out = attn @ Wo (f32 out)
    bgemm2f<<<dim3(16, 32, 1), 256, 0, stream>>>(attn_bf, H_, wT, out, H_, H_, H_);
}

// Round 3
// 627.913 us; speedup vs baseline: 1.5046x; 1.2573x over previous
//
#include <hip/hip_runtime.h>
#include <math.h>

#define B_    2
#define S_    2048
#define H_    2048
#define NH_   16
#define NOPE_ 128
#define ROPE_ 64
#define VDIM_ 128
#define RANK_ 512
#define QHD_  192   // NOPE + ROPE
#define DTOT_ 576   // RANK + ROPE

typedef short short8 __attribute__((ext_vector_type(8)));
typedef float f32x4 __attribute__((ext_vector_type(4)));

__device__ __forceinline__ unsigned short f2bf(float f) {
    unsigned u = __float_as_uint(f);
    u += 0x7fffu + ((u >> 16) & 1u);
    return (unsigned short)(u >> 16);
}
__device__ __forceinline__ float bf2f(unsigned short u) {
    return __uint_as_float((unsigned)u << 16);
}
__device__ __forceinline__ unsigned pack2bf(float a, float b) {
    return (unsigned)f2bf(a) | ((unsigned)f2bf(b) << 16);
}
__device__ __forceinline__ unsigned long long pack4bf(float a, float b, float c, float d) {
    return (unsigned long long)pack2bf(a, b) | ((unsigned long long)pack2bf(c, d) << 32);
}
union i4s8 { int4 i; short8 s; };

// Async global->LDS, 16B per lane. LDS dest = wave-uniform base + lane*16.
typedef __attribute__((address_space(3))) unsigned int lds_u32_t;
typedef __attribute__((address_space(1))) const unsigned int glob_u32_t;
__device__ __forceinline__ void async_copy16(const unsigned short* g, unsigned short* l) {
    __builtin_amdgcn_global_load_lds((glob_u32_t*)g, (lds_u32_t*)l, 16, 0, 0);
}

// ---------------------------------------------------------------------------
// cast fp32 -> bf16, 4 elems/thread.
// ---------------------------------------------------------------------------
__global__ __launch_bounds__(256) void cast_bf16(const float* __restrict__ in,
                                                 unsigned short* __restrict__ out)
{
    const size_t i = ((size_t)blockIdx.x * 256 + threadIdx.x) * 4;
    float4 v = *(const float4*)(in + i);
    *(unsigned long long*)(out + i) = pack4bf(v.x, v.y, v.z, v.w);
}

// ---------------------------------------------------------------------------
// Transpose + cast: in fp32 [Rr][Cc] (batched) -> out bf16 [Cc][Rr].
// grid (Rr/64, Cc/64, batch), 256 threads.
// ---------------------------------------------------------------------------
__global__ __launch_bounds__(256) void transpose_w(const float* __restrict__ in,
                                                   unsigned short* __restrict__ out,
                                                   int Rr, int Cc,
                                                   size_t inBatch, size_t outBatch)
{
    __shared__ unsigned short tl[64][72];
    in  += (size_t)blockIdx.z * inBatch;
    out += (size_t)blockIdx.z * outBatch;
    const int t  = threadIdx.x;
    const int r0 = blockIdx.x * 64;
    const int c0 = blockIdx.y * 64;
    const int lr = t >> 4;
    const int lc = (t & 15) * 4;
#pragma unroll
    for (int r = 0; r < 4; ++r) {
        float4 v = *(const float4*)(in + (size_t)(r0 + lr*4 + r) * Cc + c0 + lc);
        tl[lr*4 + r][lc+0] = f2bf(v.x); tl[lr*4 + r][lc+1] = f2bf(v.y);
        tl[lr*4 + r][lc+2] = f2bf(v.z); tl[lr*4 + r][lc+3] = f2bf(v.w);
    }
    __syncthreads();
#pragma unroll
    for (int r = 0; r < 4; ++r) {
        ushort4 v;
        v.x = tl[lc+0][lr*4+r]; v.y = tl[lc+1][lr*4+r];
        v.z = tl[lc+2][lr*4+r]; v.w = tl[lc+3][lr*4+r];
        *(ushort4*)(out + (size_t)(c0 + lr*4 + r) * Rr + r0 + lc) = v;
    }
}

// ---------------------------------------------------------------------------
// bf16 MFMA GEMM, m97-style: C = A[M][K](lda) @ Bt^T, Bt bf16 [N][K].
// 128x128 tile, 4 waves, BK=32, global_load_lds staging. N-guard for ragged N.
// ---------------------------------------------------------------------------
#define BGEMM_BODY(STORE_STMT)                                                     \
    __shared__ unsigned short Al[128*32];                                          \
    __shared__ unsigned short Bl[128*32];                                          \
    const int t = threadIdx.x;                                                     \
    const int wv = t >> 6;                                                         \
    const int lane = t & 63;                                                       \
    const int lq = lane & 15, quad = lane >> 4;                                    \
    const int m0 = blockIdx.y * 128, n0 = blockIdx.x * 128;                        \
    const int wrow = (wv >> 1) * 64, wcol = (wv & 1) * 64;                         \
    const int srow = lane >> 2;                                                    \
    const int scol = (lane & 3) * 8;                                               \
    f32x4 acc[4][4] = {};                                                          \
    for (int k0 = 0; k0 < K; k0 += 32) {                                           \
        _Pragma("unroll")                                                          \
        for (int pA = 0; pA < 2; ++pA) {                                           \
            const unsigned short* src =                                            \
                A + (size_t)(m0 + pA*64 + wv*16 + srow) * lda + k0 + scol;         \
            async_copy16(src, &Al[pA*2048 + wv*512]);                              \
        }                                                                          \
        _Pragma("unroll")                                                          \
        for (int pB = 0; pB < 2; ++pB) {                                           \
            int brow = n0 + pB*64 + wv*16 + srow;                                  \
            if (brow > N - 1) brow = N - 1;                                        \
            const unsigned short* src = B + (size_t)brow * K + k0 + scol;          \
            async_copy16(src, &Bl[pB*2048 + wv*512]);                              \
        }                                                                          \
        __syncthreads();                                                           \
        short8 af[4], bf[4];                                                       \
        _Pragma("unroll")                                                          \
        for (int i = 0; i < 4; ++i) {                                              \
            af[i] = *(const short8*)&Al[(wrow + i*16 + lq)*32 + quad*8];           \
            bf[i] = *(const short8*)&Bl[(wcol + i*16 + lq)*32 + quad*8];           \
        }                                                                          \
        _Pragma("unroll")                                                          \
        for (int mi = 0; mi < 4; ++mi)                                             \
            _Pragma("unroll")                                                      \
            for (int ni = 0; ni < 4; ++ni)                                         \
                acc[mi][ni] = __builtin_amdgcn_mfma_f32_16x16x32_bf16(             \
                    af[mi], bf[ni], acc[mi][ni], 0, 0, 0);                         \
        __syncthreads();                                                           \
    }                                                                              \
    _Pragma("unroll")                                                              \
    for (int mi = 0; mi < 4; ++mi)                                                 \
        _Pragma("unroll")                                                          \
        for (int ni = 0; ni < 4; ++ni) {                                           \
            int col = n0 + wcol + ni*16 + lq;                                      \
            if (col < N) {                                                         \
                _Pragma("unroll")                                                  \
                for (int r = 0; r < 4; ++r)                                        \
                    STORE_STMT;                                                    \
            }                                                                      \
        }

__global__ __launch_bounds__(256, 2) void bgemm2(const unsigned short* __restrict__ A,
                                                 int lda,
                                                 const unsigned short* __restrict__ B,
                                                 unsigned short* __restrict__ C,
                                                 int ldc, int K, int N, int qcmode)
{
    if (qcmode) {
        const int z = blockIdx.z;
        A += (size_t)(z >> 4) * S_ * (NH_*QHD_) + (z & 15) * QHD_;
        B += (size_t)(z & 15) * RANK_ * NOPE_;
        C += (size_t)z * S_ * DTOT_;
    }
    BGEMM_BODY(C[(size_t)(m0 + wrow + mi*16 + quad*4 + r) * ldc + col] = f2bf(acc[mi][ni][r]))
}

__global__ __launch_bounds__(256, 2) void bgemm2f(const unsigned short* __restrict__ A,
                                                  int lda,
                                                  const unsigned short* __restrict__ B,
                                                  float* __restrict__ C,
                                                  int ldc, int K, int N)
{
    BGEMM_BODY(C[(size_t)(m0 + wrow + mi*16 + quad*4 + r) * ldc + col] = acc[mi][ni][r])
}

// ---------------------------------------------------------------------------
// Per (b,s) row: RMSNorm ckv (bf16 in) -> k_cat[0:512]; RoPE k_pe -> [512:576].
// ---------------------------------------------------------------------------
__global__ __launch_bounds__(128) void postkv(const unsigned short* __restrict__ ckv_bf,
                                              const float* __restrict__ lnw,
                                              const int*   __restrict__ pos_ids,
                                              const float* __restrict__ cosc,
                                              const float* __restrict__ sinc,
                                              unsigned short* __restrict__ k_cat)
{
    const int row = blockIdx.x;
    const int t   = threadIdx.x;
    const unsigned short* src = ckv_bf + (size_t)row * DTOT_;
    __shared__ float red[128];

    ushort4 v = *(const ushort4*)(src + t * 4);
    float x0 = bf2f(v.x), x1 = bf2f(v.y), x2 = bf2f(v.z), x3 = bf2f(v.w);
    red[t] = x0*x0 + x1*x1 + x2*x2 + x3*x3;
    __syncthreads();
    for (int off = 64; off > 0; off >>= 1) {
        if (t < off) red[t] += red[t + off];
        __syncthreads();
    }
    const float rs = rsqrtf(red[0] / (float)RANK_ + 1e-6f);

    unsigned short* kc = k_cat + (size_t)row * DTOT_;
    *(unsigned long long*)(kc + t*4) =
        pack4bf(x0*rs*lnw[t*4+0], x1*rs*lnw[t*4+1], x2*rs*lnw[t*4+2], x3*rs*lnw[t*4+3]);

    if (t < 32) {
        const int pos = pos_ids[row];
        const float c  = cosc[pos * ROPE_ + t];
        const float sn = sinc[pos * ROPE_ + t];
        const float y0 = bf2f(src[RANK_ + 2*t]);
        const float y1 = bf2f(src[RANK_ + 2*t + 1]);
        kc[RANK_ + t]      = f2bf(y0*c - y1*sn);
        kc[RANK_ + 32 + t] = f2bf(y1*c + y0*sn);
    }
}

// ---------------------------------------------------------------------------
// RoPE q_pe (bf16 in) -> q_cat[...,512:576]. grid = B*S, 512 threads.
// ---------------------------------------------------------------------------
__global__ __launch_bounds__(512) void ropeq(const unsigned short* __restrict__ q_bf,
                                             const int*   __restrict__ pos_ids,
                                             const float* __restrict__ cosc,
                                             const float* __restrict__ sinc,
                                             unsigned short* __restrict__ q_cat)
{
    const int row = blockIdx.x;
    const int t   = threadIdx.x;
    const int h   = t >> 5;
    const int i   = t & 31;
    const int pos = pos_ids[row];
    const float c  = cosc[pos * ROPE_ + i];
    const float sn = sinc[pos * ROPE_ + i];
    const unsigned short* qrow = q_bf + (size_t)row * (NH_*QHD_) + h * QHD_ + NOPE_;
    const float x0 = bf2f(qrow[2*i]);
    const float x1 = bf2f(qrow[2*i + 1]);
    const int b = row >> 11, s = row & 2047;
    unsigned short* qc = q_cat + ((size_t)(b * NH_ + h) * S_ + s) * DTOT_ + RANK_;
    qc[i]      = f2bf(x0*c - x1*sn);
    qc[32 + i] = f2bf(x1*c + x0*sn);
}

// ---------------------------------------------------------------------------
// Vt[b,c,k] = k_cat[b,k,c] for c<512. grid (32, 8, 2).
// ---------------------------------------------------------------------------
__global__ __launch_bounds__(256) void transpose_v(const unsigned short* __restrict__ k_cat,
                                                   unsigned short* __restrict__ vt)
{
    __shared__ unsigned short tl[64][72];
    const int t  = threadIdx.x;
    const int k0 = blockIdx.x * 64;
    const int c0 = blockIdx.y * 64;
    const int b  = blockIdx.z;
    const int lr = t >> 4;
    const int lc = (t & 15) * 4;
#pragma unroll
    for (int r = 0; r < 4; ++r) {
        ushort4 v = *(const ushort4*)(k_cat + ((size_t)b * S_ + k0 + lr*4 + r) * DTOT_ + c0 + lc);
        tl[lr*4 + r][lc+0] = v.x; tl[lr*4 + r][lc+1] = v.y;
        tl[lr*4 + r][lc+2] = v.z; tl[lr*4 + r][lc+3] = v.w;
    }
    __syncthreads();
#pragma unroll
    for (int r = 0; r < 4; ++r) {
        ushort4 v;
        v.x = tl[lc+0][lr*4+r]; v.y = tl[lc+1][lr*4+r];
        v.z = tl[lc+2][lr*4+r]; v.w = tl[lc+3][lr*4+r];
        *(ushort4*)(vt + ((size_t)b * RANK_ + c0 + lr*4 + r) * S_ + k0 + lc) = v;
    }
}

__global__ __launch_bounds__(256) void wcast(const float* __restrict__ w,
                                             unsigned short* __restrict__ wbf)
{
    const size_t i = ((size_t)blockIdx.x * 256 + threadIdx.x) * 4;
    float4 v = *(const float4*)(w + i);
    *(unsigned long long*)(wbf + i) = pack4bf(v.x, v.y, v.z, v.w);
}

// ---------------------------------------------------------------------------
// Flash attention v7: 4 waves/block, 64 q-rows, 2 barriers/tile.
// v6 fixed the schedule (K+V both DMA-staged, K(t+1) under PV, V(t) under QK)
// but its G/72 swizzled-offset computation got hoisted into ~9-18 persistent
// VGPRs, spilling qf[] at the 128-VGPR cap (WRITE_SIZE 208MB). v7 keeps the
// v6 schedule but splits sK into pow2-stride regions so K staging needs only
// 3 persistent VGPRs and zero divisions:
//   sKa[32][512]: 64 granules/row. DMA (p,wv) stages full row r=p*4+wv,
//     per-lane src col = lane^(r&7); (r&7) alternates wv / wv+4 => kq0/kq1.
//   sKb[32][64] (rope): 8 granules/row. 1 DMA, thread t stages granule t,
//     src col (t&7)^((t>>3)&7) => kob.
// Read side identical swizzle algebra as v6 (proven correct + conflict-free):
// row strides 1024B/128B are both 0 mod 128.
// T13 defer-max THR=8 kept.
// ---------------------------------------------------------------------------
__device__ __forceinline__ short8 quad_transpose(unsigned d0, unsigned d1,
                                                 unsigned d2, unsigned d3,
                                                 int srcA, int srcB, bool lowquad)
{
    int e0 = __shfl((int)d0, srcA, 64);
    int e1 = __shfl((int)d1, srcA, 64);
    int e2 = __shfl((int)d2, srcA, 64);
    int e3 = __shfl((int)d3, srcA, 64);
    int f0 = __shfl((int)d0, srcB, 64);
    int f1 = __shfl((int)d1, srcB, 64);
    int f2 = __shfl((int)d2, srcB, 64);
    int f3 = __shfl((int)d3, srcB, 64);
    i4s8 u;
    u.i.x = lowquad ? e0 : e2;
    u.i.y = lowquad ? e1 : e3;
    u.i.z = lowquad ? f0 : f2;
    u.i.w = lowquad ? f1 : f3;
    return u.s;
}

__global__ __launch_bounds__(256, 2) void flash_attn4(
    const unsigned short* __restrict__ q_cat,
    const unsigned short* __restrict__ k_cat,
    const unsigned short* __restrict__ vt,
    const unsigned short* __restrict__ w2bf,
    unsigned short* __restrict__ attn_bf)
{
    __shared__ unsigned short sKa[32*512];   // 32768 B, RANK part, swizzled
    __shared__ unsigned short sKb[32*64];    //  4096 B, RoPE part, swizzled
    __shared__ unsigned short sV[512*32];    // 32768 B, XOR-swizzled contents

    const int t    = threadIdx.x;
    const int wv   = t >> 6;
    const int lane = t & 63;
    const int lq   = lane & 15;
    const int quad = lane >> 4;
    const int h    = blockIdx.x;
    const int q0   = (31 - blockIdx.y) * 64;   // longest strips first
    const int b    = blockIdx.z;
    const int srcA = lq + ((quad & 1) << 5);
    const int srcB = srcA + 16;
    const bool lowq = quad < 2;
    const int myq  = q0 + wv*16 + lq;

    // Q fragments (loop-invariant)
    const unsigned short* qrow =
        q_cat + (((size_t)(b*NH_ + h)) * S_ + q0 + wv*16 + lq) * DTOT_ + quad*8;
    short8 qf[18];
#pragma unroll
    for (int c = 0; c < 18; ++c) qf[c] = *(const short8*)(qrow + c*32);

    const unsigned short* kcb = k_cat + (size_t)b * S_ * DTOT_;
    const unsigned short* vtb = vt    + (size_t)b * RANK_ * S_;

    f32x4 o[32];
#pragma unroll
    for (int i = 0; i < 32; ++i) o[i] = (f32x4){0.f, 0.f, 0.f, 0.f};
    float m_i = -1e30f, l_i = 0.f;
    const float scale = 0.0721687836f;  // 1/sqrt(192)
    const int ntiles = (q0 >> 5) + 2;

    // --- K read-side swizzle: logical granule (row, g) lives at physical
    // g^(row&7); rows lq and 16+lq share (lq&7).
    const int swz  = lq & 7;
    const int selA = (swz >> 2) * 32;           // shorts: +32 if bit2 of swz
    const int selB = 32 - selA;
    const int kqo  = (quad ^ (swz & 3)) * 8;    // shorts within 128B block
    const unsigned short* kr0a = &sKa[lq*512 + kqo];
    const unsigned short* kr1a = &sKa[(16 + lq)*512 + kqo];
    const unsigned short* kr0b = &sKb[lq*64 + kqo];
    const unsigned short* kr1b = &sKb[(16 + lq)*64 + kqo];

    // --- K staging per-lane offsets (3 persistent VGPRs, no division)
    const int kq0 = wv*DTOT_ + (lane ^ wv)*8;        // even p: row r=p*4+wv, r&7=wv
    const int kq1 = wv*DTOT_ + (lane ^ (wv + 4))*8;  // odd  p: r&7=wv+4
    const int kob = (t >> 3)*DTOT_ + RANK_ + ((t & 7) ^ ((t >> 3) & 7))*8;

    // V staging coords (unchanged)
    const int vrow  = wv*16 + (lane >> 2);                       // + p*64
    const int vgcol = (((lane & 3) ^ ((lane >> 2) & 3))) * 8;    // XOR-swizzled group
    const int pvsw  = (quad ^ (lq & 3)) * 8;                     // PV read group

#define ISSUE_K(TPTR)                                                          \
    _Pragma("unroll")                                                          \
    for (int p = 0; p < 8; ++p)                                                \
        async_copy16((TPTR) + (p*4)*DTOT_ + ((p & 1) ? kq1 : kq0),             \
                     &sKa[p*2048 + wv*512]);                                   \
    async_copy16((TPTR) + kob, &sKb[wv*512])

    const unsigned short* ktp = kcb;      // K tile pointer, +32*DTOT_ per tile
    ISSUE_K(ktp);
    ktp += 32 * DTOT_;

    for (int tt = 0; tt < ntiles; ++tt) {
        const int k0 = tt << 5;
        __syncthreads();   // barrier1: K(tt) DMA drained -> sK valid; sV free
        {   // V stage: issue DMA EARLY — latency hidden behind QK+softmax
#pragma unroll
            for (int p = 0; p < 8; ++p) {
                const unsigned short* vsrc =
                    vtb + (size_t)(p*64 + vrow) * S_ + k0 + vgcol;
                async_copy16(vsrc, &sV[p*2048 + wv*512]);
            }
        }
        // QK^T (swizzled reads: per-lane base + compile-time offsets)
        f32x4 s0a = {0.f,0.f,0.f,0.f}, s0b = {0.f,0.f,0.f,0.f};
        f32x4 s1a = {0.f,0.f,0.f,0.f}, s1b = {0.f,0.f,0.f,0.f};
#pragma unroll
        for (int c = 0; c < 16; c += 2) {
            short8 ka0 = *(const short8*)(kr0a + c*32 + selA);
            short8 kb0 = *(const short8*)(kr0a + c*32 + selB);
            short8 ka1 = *(const short8*)(kr1a + c*32 + selA);
            short8 kb1 = *(const short8*)(kr1a + c*32 + selB);
            s0a = __builtin_amdgcn_mfma_f32_16x16x32_bf16(ka0, qf[c],   s0a, 0, 0, 0);
            s1a = __builtin_amdgcn_mfma_f32_16x16x32_bf16(ka1, qf[c],   s1a, 0, 0, 0);
            s0b = __builtin_amdgcn_mfma_f32_16x16x32_bf16(kb0, qf[c+1], s0b, 0, 0, 0);
            s1b = __builtin_amdgcn_mfma_f32_16x16x32_bf16(kb1, qf[c+1], s1b, 0, 0, 0);
        }
        {   // RoPE chunks (c = 16,17) from sKb
            short8 ka0 = *(const short8*)(kr0b + selA);
            short8 kb0 = *(const short8*)(kr0b + selB);
            short8 ka1 = *(const short8*)(kr1b + selA);
            short8 kb1 = *(const short8*)(kr1b + selB);
            s0a = __builtin_amdgcn_mfma_f32_16x16x32_bf16(ka0, qf[16], s0a, 0, 0, 0);
            s1a = __builtin_amdgcn_mfma_f32_16x16x32_bf16(ka1, qf[16], s1a, 0, 0, 0);
            s0b = __builtin_amdgcn_mfma_f32_16x16x32_bf16(kb0, qf[17], s0b, 0, 0, 0);
            s1b = __builtin_amdgcn_mfma_f32_16x16x32_bf16(kb1, qf[17], s1b, 0, 0, 0);
        }
        // online softmax (per-lane q-row = myq), T13 defer-max THR=8
        float sv[8];
#pragma unroll
        for (int r = 0; r < 4; ++r) {
            int kk0 = k0 + quad*4 + r;
            sv[r]     = (kk0      <= myq) ? (s0a[r] + s0b[r]) * scale : -1e30f;
            sv[r + 4] = (kk0 + 16 <= myq) ? (s1a[r] + s1b[r]) * scale : -1e30f;
        }
        float mx = sv[0];
#pragma unroll
        for (int i = 1; i < 8; ++i) mx = fmaxf(mx, sv[i]);
        mx = fmaxf(mx, __shfl_xor(mx, 16));
        mx = fmaxf(mx, __shfl_xor(mx, 32));
        if (!__all(mx <= m_i + 8.f)) {     // wave-uniform branch, rare after warmup
            const float m_new = fmaxf(m_i, mx);
            const float alpha = __expf(m_i - m_new);
            m_i = m_new;
            l_i *= alpha;
#pragma unroll
            for (int i = 0; i < 32; ++i) {
                o[i][0]*=alpha; o[i][1]*=alpha; o[i][2]*=alpha; o[i][3]*=alpha;
            }
        }
        float p[8]; float ls = 0.f;
#pragma unroll
        for (int i = 0; i < 8; ++i) { p[i] = __expf(sv[i] - m_i); ls += p[i]; }
        ls += __shfl_xor(ls, 16);
        ls += __shfl_xor(ls, 32);
        l_i += ls;
        short8 pb = quad_transpose(pack2bf(p[0], p[1]), pack2bf(p[2], p[3]),
                                   pack2bf(p[4], p[5]), pack2bf(p[6], p[7]),
                                   srcA, srcB, lowq);
        __syncthreads();   // barrier2: V(tt) DMA drained; all QK reads of sK done
        // K(t+1) DMA: issued now, hidden under PV, drained at next barrier1
        if (tt + 1 < ntiles) {
            ISSUE_K(ktp);
            ktp += 32 * DTOT_;
        }
        // PV (swizzled reads: 4-way max conflict)
#pragma unroll
        for (int ct = 0; ct < 32; ++ct) {
            short8 va = *(const short8*)&sV[(ct*16 + lq)*32 + pvsw];
            o[ct] = __builtin_amdgcn_mfma_f32_16x16x32_bf16(va, pb, o[ct], 0, 0, 0);
        }
    }

    // epilogue: X @ out_absorb^T, bf16 out
    const float inv = 1.0f / l_i;
    f32x4 acc[8];
#pragma unroll
    for (int i = 0; i < 8; ++i) acc[i] = (f32x4){0.f, 0.f, 0.f, 0.f};
    const unsigned short* wrow = w2bf + ((size_t)h*256 + NOPE_ + lq) * RANK_ + quad*8;
#pragma unroll
    for (int ch = 0; ch < 16; ++ch) {
        short8 xa = quad_transpose(
            pack2bf(o[2*ch][0]*inv,   o[2*ch][1]*inv),
            pack2bf(o[2*ch][2]*inv,   o[2*ch][3]*inv),
            pack2bf(o[2*ch+1][0]*inv, o[2*ch+1][1]*inv),
            pack2bf(o[2*ch+1][2]*inv, o[2*ch+1][3]*inv),
            srcA, srcB, lowq);
#pragma unroll
        for (int dt = 0; dt < 8; ++dt) {
            short8 wf = *(const short8*)(wrow + (size_t)dt*16*RANK_ + ch*32);
            acc[dt] = __builtin_amdgcn_mfma_f32_16x16x32_bf16(xa, wf, acc[dt], 0, 0, 0);
        }
    }
    unsigned short* orow =
        attn_bf + ((size_t)b * S_ + q0 + wv*16 + quad*4) * (NH_*VDIM_) + h*VDIM_ + lq;
#pragma unroll
    for (int dt = 0; dt < 8; ++dt)
#pragma unroll
        for (int r = 0; r < 4; ++r)
            orow[(size_t)r * (NH_*VDIM_) + dt*16] = f2bf(acc[dt][r]);
}

extern "C" void kernel_launch(void* const* d_in, const int* in_sizes, int n_in,
                              void* d_out, int out_size, void* d_ws, size_t ws_size,
                              hipStream_t stream)
{
    const float* hidden  = (const float*)d_in[0];
    // d_in[1] = attention_mask (guaranteed causal tril, handled analytically)
    const int*   pos_ids = (const int*)d_in[2];
    const float* cosc    = (const float*)d_in[3];
    const float* sinc    = (const float*)d_in[4];
    const float* Wq      = (const float*)d_in[5];
    const float* Wkv_a   = (const float*)d_in[6];
    const float* lnw     = (const float*)d_in[7];
    const float* Wkv_b   = (const float*)d_in[8];
    const float* Wo      = (const float*)d_in[9];
    float* out = (float*)d_out;

    const int M = B_ * S_;  // 4096
    char* ws = (char*)d_ws;
    // Workspace layout (139.5 MB total, time-disjoint aliases):
    unsigned short* hidden_bf = (unsigned short*)ws;                 // 16.78 MB (live 1-5)
    unsigned short* wqaT      = (unsigned short*)ws;                 // alias (live 10-11)
    unsigned short* attn_bf   = (unsigned short*)ws;                 // alias (live 12-14)
    unsigned short* q_bf      = (unsigned short*)(ws + 16777216);    // 25.17 MB (live 3-11)
    unsigned short* ckv_bf    = (unsigned short*)(ws + 41943040);    // 4.72 MB (live 5-6)
    unsigned short* vt        = ckv_bf;                              // alias (live 8-12)
    unsigned short* q_cat     = (unsigned short*)(ws + 46661632);    // 75.50 MB (live 7-12)
    unsigned short* k_cat     = (unsigned short*)(ws + 122159104);   // 4.72 MB (live 6-12)
    unsigned short* wT        = (unsigned short*)(ws + 126877696);   // 12.58 MB (WqT/WkvaT/WoT)
    unsigned short* w2bf      = (unsigned short*)(ws + 126877696 + 8388608); // 4.19 MB (live 9-12)

    // 1. hidden -> bf16
    cast_bf16<<<8192, 256, 0, stream>>>(hidden, hidden_bf);
    // 2. WqT = Wq^T bf16 [3072][2048]
    transpose_w<<<dim3(32, 48, 1), 256, 0, stream>>>(Wq, wT, H_, NH_*QHD_, 0, 0);
    // 3. q_bf = hidden @ Wq (bf16 out)
    bgemm2<<<dim3(24, 32, 1), 256, 0, stream>>>(hidden_bf, H_, wT, q_bf, NH_*QHD_, H_, NH_*QHD_, 0);
    // 4. WkvaT bf16 [576][2048]
    transpose_w<<<dim3(32, 9, 1), 256, 0, stream>>>(Wkv_a, wT, H_, DTOT_, 0, 0);
    // 5. ckv_bf = hidden @ Wkv_a (bf16 out, ragged N=576)
    bgemm2<<<dim3(5, 32, 1), 256, 0, stream>>>(hidden_bf, H_, wT, ckv_bf, DTOT_, H_, DTOT_, 0);
    // 6. RMSNorm + k_pe RoPE -> k_cat
    postkv<<<M, 128, 0, stream>>>(ckv_bf, lnw, pos_ids, cosc, sinc, k_cat);
    // 7. q_pe RoPE -> q_cat[...,512:576]
    ropeq<<<M, 512, 0, stream>>>(q_bf, pos_ids, cosc, sinc, q_cat);
    // 8. Vt = transpose of k_cat[:, :512]
    transpose_v<<<dim3(S_/64, RANK_/64, B_), 256, 0, stream>>>(k_cat, vt);
    // 9. Wkv_b -> bf16 (flash epilogue weights)
    wcast<<<(NH_*256*RANK_)/1024, 256, 0, stream>>>(Wkv_b, w2bf);
    // 10. wqaT[h] = (Wkv_b[h][0:128])^T bf16 [512][128]
    transpose_w<<<dim3(2, 8, 16), 256, 0, stream>>>(Wkv_b, wqaT, NOPE_, RANK_,
                                                    (size_t)256*RANK_, (size_t)RANK_*NOPE_);
    // 11. q_cat[...,0:512] = q_nope @ q_absorb (batched, K=128)
    bgemm2<<<dim3(4, 16, 32), 256, 0, stream>>>(q_bf, NH_*QHD_, wqaT, q_cat, DTOT_, NOPE_, RANK_, 1);
    // 12. flash attention -> attn_bf (bf16)
    flash_attn4<<<dim3(NH_, S_/64, B_), 256, 0, stream>>>(q_cat, k_cat, vt, w2bf, attn_bf);
    // 13. WoT bf16 [2048][2048]
    transpose_w<<<dim3(32, 32, 1), 256, 0, stream>>>(Wo, wT, H_, H_, 0, 0);
    // 14. out = attn @ Wo (f32 out)
    bgemm2f<<<dim3(16, 32, 1), 256, 0, stream>>>(attn_bf, H_, wT, out, H_, H_, H_);
}

// Round 5
// 523.558 us; speedup vs baseline: 1.8045x; 1.1993x over previous
//
#include <hip/hip_runtime.h>
#include <math.h>

#define B_    2
#define S_    2048
#define H_    2048
#define NH_   16
#define NOPE_ 128
#define ROPE_ 64
#define VDIM_ 128
#define RANK_ 512
#define QHD_  192   // NOPE + ROPE
#define DTOT_ 576   // RANK + ROPE

typedef short short8 __attribute__((ext_vector_type(8)));
typedef float f32x4 __attribute__((ext_vector_type(4)));

__device__ __forceinline__ unsigned short f2bf(float f) {
    unsigned u = __float_as_uint(f);
    u += 0x7fffu + ((u >> 16) & 1u);
    return (unsigned short)(u >> 16);
}
__device__ __forceinline__ float bf2f(unsigned short u) {
    return __uint_as_float((unsigned)u << 16);
}
__device__ __forceinline__ unsigned pack2bf(float a, float b) {
    return (unsigned)f2bf(a) | ((unsigned)f2bf(b) << 16);
}
__device__ __forceinline__ unsigned long long pack4bf(float a, float b, float c, float d) {
    return (unsigned long long)pack2bf(a, b) | ((unsigned long long)pack2bf(c, d) << 32);
}
union i4s8 { int4 i; short8 s; };

// Async global->LDS, 16B per lane. LDS dest = wave-uniform base + lane*16.
typedef __attribute__((address_space(3))) unsigned int lds_u32_t;
typedef __attribute__((address_space(1))) const unsigned int glob_u32_t;
__device__ __forceinline__ void async_copy16(const unsigned short* g, unsigned short* l) {
    __builtin_amdgcn_global_load_lds((glob_u32_t*)g, (lds_u32_t*)l, 16, 0, 0);
}

// ---------------------------------------------------------------------------
// cast fp32 -> bf16, 4 elems/thread.
// ---------------------------------------------------------------------------
__global__ __launch_bounds__(256) void cast_bf16(const float* __restrict__ in,
                                                 unsigned short* __restrict__ out)
{
    const size_t i = ((size_t)blockIdx.x * 256 + threadIdx.x) * 4;
    float4 v = *(const float4*)(in + i);
    *(unsigned long long*)(out + i) = pack4bf(v.x, v.y, v.z, v.w);
}

// ---------------------------------------------------------------------------
// Transpose + cast: in fp32 [Rr][Cc] (batched) -> out bf16 [Cc][Rr].
// grid (Rr/64, Cc/64, batch), 256 threads.
// ---------------------------------------------------------------------------
__global__ __launch_bounds__(256) void transpose_w(const float* __restrict__ in,
                                                   unsigned short* __restrict__ out,
                                                   int Rr, int Cc,
                                                   size_t inBatch, size_t outBatch)
{
    __shared__ unsigned short tl[64][72];
    in  += (size_t)blockIdx.z * inBatch;
    out += (size_t)blockIdx.z * outBatch;
    const int t  = threadIdx.x;
    const int r0 = blockIdx.x * 64;
    const int c0 = blockIdx.y * 64;
    const int lr = t >> 4;
    const int lc = (t & 15) * 4;
#pragma unroll
    for (int r = 0; r < 4; ++r) {
        float4 v = *(const float4*)(in + (size_t)(r0 + lr*4 + r) * Cc + c0 + lc);
        tl[lr*4 + r][lc+0] = f2bf(v.x); tl[lr*4 + r][lc+1] = f2bf(v.y);
        tl[lr*4 + r][lc+2] = f2bf(v.z); tl[lr*4 + r][lc+3] = f2bf(v.w);
    }
    __syncthreads();
#pragma unroll
    for (int r = 0; r < 4; ++r) {
        ushort4 v;
        v.x = tl[lc+0][lr*4+r]; v.y = tl[lc+1][lr*4+r];
        v.z = tl[lc+2][lr*4+r]; v.w = tl[lc+3][lr*4+r];
        *(ushort4*)(out + (size_t)(c0 + lr*4 + r) * Rr + r0 + lc) = v;
    }
}

// ---------------------------------------------------------------------------
// bf16 MFMA GEMM, m97-style: C = A[M][K](lda) @ Bt^T, Bt bf16 [N][K](ldb).
// 128x128 tile, 4 waves, BK=32, global_load_lds staging. N-guard for ragged N.
// mode 1: batched q-absorb. mode 2: batched VW^T = out_absorb @ k_cat^T.
// ---------------------------------------------------------------------------
#define BGEMM_BODY(STORE_STMT)                                                     \
    __shared__ unsigned short Al[128*32];                                          \
    __shared__ unsigned short Bl[128*32];                                          \
    const int t = threadIdx.x;                                                     \
    const int wv = t >> 6;                                                         \
    const int lane = t & 63;                                                       \
    const int lq = lane & 15, quad = lane >> 4;                                    \
    const int m0 = blockIdx.y * 128, n0 = blockIdx.x * 128;                        \
    const int wrow = (wv >> 1) * 64, wcol = (wv & 1) * 64;                         \
    const int srow = lane >> 2;                                                    \
    const int scol = (lane & 3) * 8;                                               \
    f32x4 acc[4][4] = {};                                                          \
    for (int k0 = 0; k0 < K; k0 += 32) {                                           \
        _Pragma("unroll")                                                          \
        for (int pA = 0; pA < 2; ++pA) {                                           \
            const unsigned short* src =                                            \
                A + (size_t)(m0 + pA*64 + wv*16 + srow) * lda + k0 + scol;         \
            async_copy16(src, &Al[pA*2048 + wv*512]);                              \
        }                                                                          \
        _Pragma("unroll")                                                          \
        for (int pB = 0; pB < 2; ++pB) {                                           \
            int brow = n0 + pB*64 + wv*16 + srow;                                  \
            if (brow > N - 1) brow = N - 1;                                        \
            const unsigned short* src = B + (size_t)brow * ldb + k0 + scol;        \
            async_copy16(src, &Bl[pB*2048 + wv*512]);                              \
        }                                                                          \
        __syncthreads();                                                           \
        short8 af[4], bf[4];                                                       \
        _Pragma("unroll")                                                          \
        for (int i = 0; i < 4; ++i) {                                              \
            af[i] = *(const short8*)&Al[(wrow + i*16 + lq)*32 + quad*8];           \
            bf[i] = *(const short8*)&Bl[(wcol + i*16 + lq)*32 + quad*8];           \
        }                                                                          \
        _Pragma("unroll")                                                          \
        for (int mi = 0; mi < 4; ++mi)                                             \
            _Pragma("unroll")                                                      \
            for (int ni = 0; ni < 4; ++ni)                                         \
                acc[mi][ni] = __builtin_amdgcn_mfma_f32_16x16x32_bf16(             \
                    af[mi], bf[ni], acc[mi][ni], 0, 0, 0);                         \
        __syncthreads();                                                           \
    }                                                                              \
    _Pragma("unroll")                                                              \
    for (int mi = 0; mi < 4; ++mi)                                                 \
        _Pragma("unroll")                                                          \
        for (int ni = 0; ni < 4; ++ni) {                                           \
            int col = n0 + wcol + ni*16 + lq;                                      \
            if (col < N) {                                                         \
                _Pragma("unroll")                                                  \
                for (int r = 0; r < 4; ++r)                                        \
                    STORE_STMT;                                                    \
            }                                                                      \
        }

__global__ __launch_bounds__(256, 2) void bgemm2(const unsigned short* __restrict__ A,
                                                 int lda,
                                                 const unsigned short* __restrict__ B,
                                                 int ldb,
                                                 unsigned short* __restrict__ C,
                                                 int ldc, int K, int N, int qcmode)
{
    if (qcmode == 1) {
        const int z = blockIdx.z;
        A += (size_t)(z >> 4) * S_ * (NH_*QHD_) + (z & 15) * QHD_;
        B += (size_t)(z & 15) * RANK_ * NOPE_;
        C += (size_t)z * S_ * DTOT_;
    } else if (qcmode == 2) {
        // VW^T[b,h] [128][2048] = out_absorb[h] [128][512] @ (k_cat[b][:, :512])^T
        const int z = blockIdx.z;
        A += (size_t)(z & 15) * 256 * RANK_ + (size_t)NOPE_ * RANK_;
        B += (size_t)(z >> 4) * S_ * DTOT_;
        C += (size_t)z * VDIM_ * S_;
    }
    BGEMM_BODY(C[(size_t)(m0 + wrow + mi*16 + quad*4 + r) * ldc + col] = f2bf(acc[mi][ni][r]))
}

__global__ __launch_bounds__(256, 2) void bgemm2f(const unsigned short* __restrict__ A,
                                                  int lda,
                                                  const unsigned short* __restrict__ B,
                                                  int ldb,
                                                  float* __restrict__ C,
                                                  int ldc, int K, int N)
{
    BGEMM_BODY(C[(size_t)(m0 + wrow + mi*16 + quad*4 + r) * ldc + col] = acc[mi][ni][r])
}

// ---------------------------------------------------------------------------
// Per (b,s) row: RMSNorm ckv (bf16 in) -> k_cat[0:512]; RoPE k_pe -> [512:576].
// ---------------------------------------------------------------------------
__global__ __launch_bounds__(128) void postkv(const unsigned short* __restrict__ ckv_bf,
                                              const float* __restrict__ lnw,
                                              const int*   __restrict__ pos_ids,
                                              const float* __restrict__ cosc,
                                              const float* __restrict__ sinc,
                                              unsigned short* __restrict__ k_cat)
{
    const int row = blockIdx.x;
    const int t   = threadIdx.x;
    const unsigned short* src = ckv_bf + (size_t)row * DTOT_;
    __shared__ float red[128];

    ushort4 v = *(const ushort4*)(src + t * 4);
    float x0 = bf2f(v.x), x1 = bf2f(v.y), x2 = bf2f(v.z), x3 = bf2f(v.w);
    red[t] = x0*x0 + x1*x1 + x2*x2 + x3*x3;
    __syncthreads();
    for (int off = 64; off > 0; off >>= 1) {
        if (t < off) red[t] += red[t + off];
        __syncthreads();
    }
    const float rs = rsqrtf(red[0] / (float)RANK_ + 1e-6f);

    unsigned short* kc = k_cat + (size_t)row * DTOT_;
    *(unsigned long long*)(kc + t*4) =
        pack4bf(x0*rs*lnw[t*4+0], x1*rs*lnw[t*4+1], x2*rs*lnw[t*4+2], x3*rs*lnw[t*4+3]);

    if (t < 32) {
        const int pos = pos_ids[row];
        const float c  = cosc[pos * ROPE_ + t];
        const float sn = sinc[pos * ROPE_ + t];
        const float y0 = bf2f(src[RANK_ + 2*t]);
        const float y1 = bf2f(src[RANK_ + 2*t + 1]);
        kc[RANK_ + t]      = f2bf(y0*c - y1*sn);
        kc[RANK_ + 32 + t] = f2bf(y1*c + y0*sn);
    }
}

// ---------------------------------------------------------------------------
// RoPE q_pe (bf16 in) -> q_cat[...,512:576]. grid = B*S, 512 threads.
// ---------------------------------------------------------------------------
__global__ __launch_bounds__(512) void ropeq(const unsigned short* __restrict__ q_bf,
                                             const int*   __restrict__ pos_ids,
                                             const float* __restrict__ cosc,
                                             const float* __restrict__ sinc,
                                             unsigned short* __restrict__ q_cat)
{
    const int row = blockIdx.x;
    const int t   = threadIdx.x;
    const int h   = t >> 5;
    const int i   = t & 31;
    const int pos = pos_ids[row];
    const float c  = cosc[pos * ROPE_ + i];
    const float sn = sinc[pos * ROPE_ + i];
    const unsigned short* qrow = q_bf + (size_t)row * (NH_*QHD_) + h * QHD_ + NOPE_;
    const float x0 = bf2f(qrow[2*i]);
    const float x1 = bf2f(qrow[2*i + 1]);
    const int b = row >> 11, s = row & 2047;
    unsigned short* qc = q_cat + ((size_t)(b * NH_ + h) * S_ + s) * DTOT_ + RANK_;
    qc[i]      = f2bf(x0*c - x1*sn);
    qc[32 + i] = f2bf(x1*c + x0*sn);
}

__global__ __launch_bounds__(256) void wcast(const float* __restrict__ w,
                                             unsigned short* __restrict__ wbf)
{
    const size_t i = ((size_t)blockIdx.x * 256 + threadIdx.x) * 4;
    float4 v = *(const float4*)(w + i);
    *(unsigned long long*)(wbf + i) = pack4bf(v.x, v.y, v.z, v.w);
}

// ---------------------------------------------------------------------------
// Flash attention v8: absorb-V. Round-3 counters showed LDS-throughput-bound
// (~1000 LDS-cy/tile-wave, 224us floor). Fix: precompute VW^T = out_absorb @
// ckv^T [128][S] per (b,h); then o = P @ VW directly. Per tile-wave:
//   PV: 8 MFMAs + 8 b128 reads (was 32+32); V-DMA 2 (was 8); epilogue GEMM
//   and its w2 reads GONE; o = 32 AGPRs (was 128).
// LDS ~590 cy/tile-wave -> ~131us floor. K path unchanged from v7 (proven).
// V swizzle upgraded to row-bits[1:2] XOR (2-way instead of 4-way).
// ---------------------------------------------------------------------------
__device__ __forceinline__ short8 quad_transpose(unsigned d0, unsigned d1,
                                                 unsigned d2, unsigned d3,
                                                 int srcA, int srcB, bool lowquad)
{
    int e0 = __shfl((int)d0, srcA, 64);
    int e1 = __shfl((int)d1, srcA, 64);
    int e2 = __shfl((int)d2, srcA, 64);
    int e3 = __shfl((int)d3, srcA, 64);
    int f0 = __shfl((int)d0, srcB, 64);
    int f1 = __shfl((int)d1, srcB, 64);
    int f2 = __shfl((int)d2, srcB, 64);
    int f3 = __shfl((int)d3, srcB, 64);
    i4s8 u;
    u.i.x = lowquad ? e0 : e2;
    u.i.y = lowquad ? e1 : e3;
    u.i.z = lowquad ? f0 : f2;
    u.i.w = lowquad ? f1 : f3;
    return u.s;
}

__global__ __launch_bounds__(256, 2) void flash_attn4(
    const unsigned short* __restrict__ q_cat,
    const unsigned short* __restrict__ k_cat,
    const unsigned short* __restrict__ vwt,
    unsigned short* __restrict__ attn_bf)
{
    __shared__ unsigned short sKa[32*512];   // 32768 B, RANK part, swizzled
    __shared__ unsigned short sKb[32*64];    //  4096 B, RoPE part, swizzled
    __shared__ unsigned short sVW[128*32];   //  8192 B, VW^T tile, swizzled

    const int t    = threadIdx.x;
    const int wv   = t >> 6;
    const int lane = t & 63;
    const int lq   = lane & 15;
    const int quad = lane >> 4;
    const int h    = blockIdx.x;
    const int q0   = (31 - blockIdx.y) * 64;   // longest strips first
    const int b    = blockIdx.z;
    const int srcA = lq + ((quad & 1) << 5);
    const int srcB = srcA + 16;
    const bool lowq = quad < 2;
    const int myq  = q0 + wv*16 + lq;

    // Q fragments (loop-invariant)
    const unsigned short* qrow =
        q_cat + (((size_t)(b*NH_ + h)) * S_ + q0 + wv*16 + lq) * DTOT_ + quad*8;
    short8 qf[18];
#pragma unroll
    for (int c = 0; c < 18; ++c) qf[c] = *(const short8*)(qrow + c*32);

    const unsigned short* kcb = k_cat + (size_t)b * S_ * DTOT_;
    const unsigned short* vtb = vwt + (size_t)(b*NH_ + h) * VDIM_ * S_;

    f32x4 o[8];
#pragma unroll
    for (int i = 0; i < 8; ++i) o[i] = (f32x4){0.f, 0.f, 0.f, 0.f};
    float m_i = -1e30f, l_i = 0.f;
    const float scale = 0.0721687836f;  // 1/sqrt(192)
    const int ntiles = (q0 >> 5) + 2;

    // --- K read-side swizzle: logical granule (row, g) lives at physical
    // g^(row&7); rows lq and 16+lq share (lq&7).
    const int swz  = lq & 7;
    const int selA = (swz >> 2) * 32;           // shorts: +32 if bit2 of swz
    const int selB = 32 - selA;
    const int kqo  = (quad ^ (swz & 3)) * 8;    // shorts within 128B block
    const unsigned short* kr0a = &sKa[lq*512 + kqo];
    const unsigned short* kr1a = &sKa[(16 + lq)*512 + kqo];
    const unsigned short* kr0b = &sKb[lq*64 + kqo];
    const unsigned short* kr1b = &sKb[(16 + lq)*64 + kqo];

    // --- K staging per-lane offsets (3 persistent VGPRs, no division)
    const int kq0 = wv*DTOT_ + (lane ^ wv)*8;        // even p: row r=p*4+wv, r&7=wv
    const int kq1 = wv*DTOT_ + (lane ^ (wv + 4))*8;  // odd  p: r&7=wv+4
    const int kob = (t >> 3)*DTOT_ + RANK_ + ((t & 7) ^ ((t >> 3) & 7))*8;

    // V staging coords: row r = p*64 + wv*16 + (lane>>2); physical col
    // (lane&3) stores logical k-granule (lane&3)^((r>>1)&3) -> 2-way reads.
    const int vrow  = wv*16 + (lane >> 2);                       // + p*64
    const int vgcol = (((lane & 3) ^ ((lane >> 3) & 3))) * 8;    // swizzled source
    const int pvsw  = (quad ^ ((lq >> 1) & 3)) * 8;              // PV read group

#define ISSUE_K(TPTR)                                                          \
    _Pragma("unroll")                                                          \
    for (int p = 0; p < 8; ++p)                                                \
        async_copy16((TPTR) + (p*4)*DTOT_ + ((p & 1) ? kq1 : kq0),             \
                     &sKa[p*2048 + wv*512]);                                   \
    async_copy16((TPTR) + kob, &sKb[wv*512])

    const unsigned short* ktp = kcb;      // K tile pointer, +32*DTOT_ per tile
    ISSUE_K(ktp);
    ktp += 32 * DTOT_;

    for (int tt = 0; tt < ntiles; ++tt) {
        const int k0 = tt << 5;
        __syncthreads();   // barrier1: K(tt) DMA drained -> sK valid; sVW free
        {   // VW stage: 2 DMAs, hidden behind QK+softmax
#pragma unroll
            for (int p = 0; p < 2; ++p) {
                const unsigned short* vsrc =
                    vtb + (size_t)(p*64 + vrow) * S_ + k0 + vgcol;
                async_copy16(vsrc, &sVW[p*2048 + wv*512]);
            }
        }
        // QK^T (swizzled reads: per-lane base + compile-time offsets)
        f32x4 s0a = {0.f,0.f,0.f,0.f}, s0b = {0.f,0.f,0.f,0.f};
        f32x4 s1a = {0.f,0.f,0.f,0.f}, s1b = {0.f,0.f,0.f,0.f};
#pragma unroll
        for (int c = 0; c < 16; c += 2) {
            short8 ka0 = *(const short8*)(kr0a + c*32 + selA);
            short8 kb0 = *(const short8*)(kr0a + c*32 + selB);
            short8 ka1 = *(const short8*)(kr1a + c*32 + selA);
            short8 kb1 = *(const short8*)(kr1a + c*32 + selB);
            s0a = __builtin_amdgcn_mfma_f32_16x16x32_bf16(ka0, qf[c],   s0a, 0, 0, 0);
            s1a = __builtin_amdgcn_mfma_f32_16x16x32_bf16(ka1, qf[c],   s1a, 0, 0, 0);
            s0b = __builtin_amdgcn_mfma_f32_16x16x32_bf16(kb0, qf[c+1], s0b, 0, 0, 0);
            s1b = __builtin_amdgcn_mfma_f32_16x16x32_bf16(kb1, qf[c+1], s1b, 0, 0, 0);
        }
        {   // RoPE chunks (c = 16,17) from sKb
            short8 ka0 = *(const short8*)(kr0b + selA);
            short8 kb0 = *(const short8*)(kr0b + selB);
            short8 ka1 = *(const short8*)(kr1b + selA);
            short8 kb1 = *(const short8*)(kr1b + selB);
            s0a = __builtin_amdgcn_mfma_f32_16x16x32_bf16(ka0, qf[16], s0a, 0, 0, 0);
            s1a = __builtin_amdgcn_mfma_f32_16x16x32_bf16(ka1, qf[16], s1a, 0, 0, 0);
            s0b = __builtin_amdgcn_mfma_f32_16x16x32_bf16(kb0, qf[17], s0b, 0, 0, 0);
            s1b = __builtin_amdgcn_mfma_f32_16x16x32_bf16(kb1, qf[17], s1b, 0, 0, 0);
        }
        // online softmax (per-lane q-row = myq), T13 defer-max THR=8
        float sv[8];
#pragma unroll
        for (int r = 0; r < 4; ++r) {
            int kk0 = k0 + quad*4 + r;
            sv[r]     = (kk0      <= myq) ? (s0a[r] + s0b[r]) * scale : -1e30f;
            sv[r + 4] = (kk0 + 16 <= myq) ? (s1a[r] + s1b[r]) * scale : -1e30f;
        }
        float mx = sv[0];
#pragma unroll
        for (int i = 1; i < 8; ++i) mx = fmaxf(mx, sv[i]);
        mx = fmaxf(mx, __shfl_xor(mx, 16));
        mx = fmaxf(mx, __shfl_xor(mx, 32));
        if (!__all(mx <= m_i + 8.f)) {     // wave-uniform branch, rare after warmup
            const float m_new = fmaxf(m_i, mx);
            const float alpha = __expf(m_i - m_new);
            m_i = m_new;
            l_i *= alpha;
#pragma unroll
            for (int i = 0; i < 8; ++i) {
                o[i][0]*=alpha; o[i][1]*=alpha; o[i][2]*=alpha; o[i][3]*=alpha;
            }
        }
        float p[8]; float ls = 0.f;
#pragma unroll
        for (int i = 0; i < 8; ++i) { p[i] = __expf(sv[i] - m_i); ls += p[i]; }
        ls += __shfl_xor(ls, 16);
        ls += __shfl_xor(ls, 32);
        l_i += ls;
        short8 pb = quad_transpose(pack2bf(p[0], p[1]), pack2bf(p[2], p[3]),
                                   pack2bf(p[4], p[5]), pack2bf(p[6], p[7]),
                                   srcA, srcB, lowq);
        __syncthreads();   // barrier2: VW(tt) DMA drained; all QK reads of sK done
        // K(t+1) DMA: issued now, hidden under PV, drained at next barrier1
        if (tt + 1 < ntiles) {
            ISSUE_K(ktp);
            ktp += 32 * DTOT_;
        }
        // PV: o[dt] covers d = dt*16 + quad*4 + r for q-col = myq
#pragma unroll
        for (int dt = 0; dt < 8; ++dt) {
            short8 va = *(const short8*)&sVW[(dt*16 + lq)*32 + pvsw];
            o[dt] = __builtin_amdgcn_mfma_f32_16x16x32_bf16(va, pb, o[dt], 0, 0, 0);
        }
    }

    // store: transpose o (rows=d, cols=q) -> lane holds q=lq, 8 consecutive d.
    const float inv = 1.0f / l_i;
    unsigned short* orow =
        attn_bf + ((size_t)b * S_ + q0 + wv*16 + lq) * (NH_*VDIM_) + h*VDIM_;
#pragma unroll
    for (int dt2 = 0; dt2 < 4; ++dt2) {
        short8 xa = quad_transpose(
            pack2bf(o[2*dt2][0]*inv,   o[2*dt2][1]*inv),
            pack2bf(o[2*dt2][2]*inv,   o[2*dt2][3]*inv),
            pack2bf(o[2*dt2+1][0]*inv, o[2*dt2+1][1]*inv),
            pack2bf(o[2*dt2+1][2]*inv, o[2*dt2+1][3]*inv),
            srcA, srcB, lowq);
        *(short8*)(orow + dt2*32 + quad*8) = xa;
    }
}

extern "C" void kernel_launch(void* const* d_in, const int* in_sizes, int n_in,
                              void* d_out, int out_size, void* d_ws, size_t ws_size,
                              hipStream_t stream)
{
    const float* hidden  = (const float*)d_in[0];
    // d_in[1] = attention_mask (guaranteed causal tril, handled analytically)
    const int*   pos_ids = (const int*)d_in[2];
    const float* cosc    = (const float*)d_in[3];
    const float* sinc    = (const float*)d_in[4];
    const float* Wq      = (const float*)d_in[5];
    const float* Wkv_a   = (const float*)d_in[6];
    const float* lnw     = (const float*)d_in[7];
    const float* Wkv_b   = (const float*)d_in[8];
    const float* Wo      = (const float*)d_in[9];
    float* out = (float*)d_out;

    const int M = B_ * S_;  // 4096
    char* ws = (char*)d_ws;
    // Workspace layout (139.5 MB total, time-disjoint aliases):
    unsigned short* hidden_bf = (unsigned short*)ws;                 // 16.78 MB (live 1-5)
    unsigned short* vwT       = (unsigned short*)ws;                 // alias 16.78 MB (live 9-12)
    unsigned short* q_bf      = (unsigned short*)(ws + 16777216);    // 25.17 MB (live 3-11)
    unsigned short* attn_bf   = q_bf;                                // alias (live 12-14, after q_bf dead)
    unsigned short* ckv_bf    = (unsigned short*)(ws + 41943040);    // 4.72 MB (live 5-6)
    unsigned short* wqaT      = ckv_bf;                              // alias 2.10 MB (live 10-11)
    unsigned short* q_cat     = (unsigned short*)(ws + 46661632);    // 75.50 MB (live 7-12)
    unsigned short* k_cat     = (unsigned short*)(ws + 122159104);   // 4.72 MB (live 6-12)
    unsigned short* wT        = (unsigned short*)(ws + 126877696);   // 12.58 MB (WqT/WkvaT/WoT)
    unsigned short* w2bf      = (unsigned short*)(ws + 126877696 + 8388608); // 4.19 MB (live 8-9)

    // 1. hidden -> bf16
    cast_bf16<<<8192, 256, 0, stream>>>(hidden, hidden_bf);
    // 2. WqT = Wq^T bf16 [3072][2048]
    transpose_w<<<dim3(32, 48, 1), 256, 0, stream>>>(Wq, wT, H_, NH_*QHD_, 0, 0);
    // 3. q_bf = hidden @ Wq (bf16 out)
    bgemm2<<<dim3(24, 32, 1), 256, 0, stream>>>(hidden_bf, H_, wT, H_, q_bf, NH_*QHD_, H_, NH_*QHD_, 0);
    // 4. WkvaT bf16 [576][2048]
    transpose_w<<<dim3(32, 9, 1), 256, 0, stream>>>(Wkv_a, wT, H_, DTOT_, 0, 0);
    // 5. ckv_bf = hidden @ Wkv_a (bf16 out, ragged N=576)
    bgemm2<<<dim3(5, 32, 1), 256, 0, stream>>>(hidden_bf, H_, wT, H_, ckv_bf, DTOT_, H_, DTOT_, 0);
    // 6. RMSNorm + k_pe RoPE -> k_cat
    postkv<<<M, 128, 0, stream>>>(ckv_bf, lnw, pos_ids, cosc, sinc, k_cat);
    // 7. q_pe RoPE -> q_cat[...,512:576]
    ropeq<<<M, 512, 0, stream>>>(q_bf, pos_ids, cosc, sinc, q_cat);
    // 8. Wkv_b -> bf16
    wcast<<<(NH_*256*RANK_)/1024, 256, 0, stream>>>(Wkv_b, w2bf);
    // 9. vwT[b,h] = out_absorb[h] @ k_cat[b][:, :512]^T  (bf16, [128][2048] per z)
    bgemm2<<<dim3(16, 1, 32), 256, 0, stream>>>(w2bf, RANK_, k_cat, DTOT_, vwT, S_, RANK_, S_, 2);
    // 10. wqaT[h] = (Wkv_b[h][0:128])^T bf16 [512][128]
    transpose_w<<<dim3(2, 8, 16), 256, 0, stream>>>(Wkv_b, wqaT, NOPE_, RANK_,
                                                    (size_t)256*RANK_, (size_t)RANK_*NOPE_);
    // 11. q_cat[...,0:512] = q_nope @ q_absorb (batched, K=128)
    bgemm2<<<dim3(4, 16, 32), 256, 0, stream>>>(q_bf, NH_*QHD_, wqaT, NOPE_, q_cat, DTOT_, NOPE_, RANK_, 1);
    // 12. flash attention (absorb-V) -> attn_bf (bf16)
    flash_attn4<<<dim3(NH_, S_/64, B_), 256, 0, stream>>>(q_cat, k_cat, vwT, attn_bf);
    // 13. WoT bf16 [2048][2048]
    transpose_w<<<dim3(32, 32, 1), 256, 0, stream>>>(Wo, wT, H_, H_, 0, 0);
    // 14. out = attn @ Wo (f32 out)
    bgemm2f<<<dim3(16, 32, 1), 256, 0, stream>>>(attn_bf, H_, wT, H_, out, H_, H_, H_);
}